// Round 7
// baseline (360.986 us; speedup 1.0000x reference)
//
#include <hip/hip_runtime.h>

#define N_ROWS 32768
#define DIM 256
#define KCODES 1024

#define Q_N (N_ROWS * DIM)          // 8388608
#define IDX_OFF Q_N                 // 8388608
#define ZERO_OFF (Q_N + N_ROWS)     // 8421376
#define LOSS_OFF (ZERO_OFF + 1)
#define PERP_OFF (ZERO_OFF + 2)

// Safe ambiguity margin (score units): np's d-quantization can only reorder
// codes whose exact scores differ by < 2*ulp(d~256)=6.1e-5; our fast-path
// score error is <~5e-6. 8e-5 covers both with slack. (was 2e-4 -> ~2.5x rows)
#define THETA 8.0e-5f

#define TC 32                 // codes per LDS tile
#define NT (KCODES / TC)      // 32 tiles

typedef __attribute__((ext_vector_type(8))) short bf16x8;
typedef __attribute__((ext_vector_type(4))) float f32x4;
typedef unsigned short u16;

// ws layout (bytes):
//   [0, 4096)          sen float[K]
//   [4096, 8192)       hist uint[K]
//   [8192, 8200)       double loss_acc
//   [8200, 8204)       uint ambig_count
//   [8448, 139520)     szn float[32768]  (numpy-pairwise ||z||^2)
//   [139520, 270592)   uint worklist[32768]
//   [270592, 794880)   ehi u16[262144]   (bf16 of -e)
//   [794880, 1319168)  elo u16[262144]   (bf16 of (-e) - ehi)
// zhi/zlo live in d_out's q region until vq_gather overwrites it.

__device__ inline u16 bf16rne(float f) {
    unsigned u = __float_as_uint(f);
    return (u16)((u + 0x7FFFu + ((u >> 16) & 1u)) >> 16);
}
__device__ inline float bf16f(u16 h) { return __uint_as_float((unsigned)h << 16); }

typedef __attribute__((address_space(3))) unsigned int as3_uint;
typedef __attribute__((address_space(1))) const unsigned int as1_uint;
__device__ inline void gload_lds16(const void* g, void* l) {
    __builtin_amdgcn_global_load_lds((as1_uint*)g, (as3_uint*)l, 16, 0, 0);
}

// fused: init(hist/loss/count) + accurate ||e||^2 + negated bf16 hi/lo splits.
__global__ __launch_bounds__(256) void vq_prep_cb(const float* __restrict__ cb,
                                                  float* __restrict__ sen,
                                                  u16* __restrict__ ehi,
                                                  u16* __restrict__ elo,
                                                  unsigned* __restrict__ hist,
                                                  double* __restrict__ loss_acc,
                                                  unsigned* __restrict__ count) {
    int b = blockIdx.x, t = threadIdx.x;
    if (b < 4) {
        hist[b * 256 + t] = 0u;
        if (b == 0 && t == 0) { *loss_acc = 0.0; *count = 0u; }
    }
    int code = b * 4 + (t >> 6);
    int lane = t & 63;
    size_t eoff = (size_t)code * DIM + lane * 4;
    float4 v = *(const float4*)(cb + eoff);
    double s = (double)v.x * v.x + (double)v.y * v.y + (double)v.z * v.z + (double)v.w * v.w;
    #pragma unroll
    for (int off = 32; off; off >>= 1) s += __shfl_down(s, off, 64);
    if (lane == 0) sen[code] = (float)s;
    v.x = -v.x; v.y = -v.y; v.z = -v.z; v.w = -v.w;
    ushort4 h, l;
    h.x = bf16rne(v.x); l.x = bf16rne(v.x - bf16f(h.x));
    h.y = bf16rne(v.y); l.y = bf16rne(v.y - bf16f(h.y));
    h.z = bf16rne(v.z); l.z = bf16rne(v.z - bf16f(h.z));
    h.w = bf16rne(v.w); l.w = bf16rne(v.w - bf16f(h.w));
    *(ushort4*)(ehi + eoff) = h;
    *(ushort4*)(elo + eoff) = l;
}

// fused: z -> bf16 hi/lo splits + numpy-pairwise-exact ||z||^2 (np fp32
// pairwise_sum order reproduced bit-exactly via __fmul_rn/__fadd_rn).
__global__ __launch_bounds__(256) void vq_prep_z(const float* __restrict__ z,
                                                 u16* __restrict__ zhi,
                                                 u16* __restrict__ zlo,
                                                 float* __restrict__ szn) {
    __shared__ float zs[4 * 264];
    size_t base = (size_t)blockIdx.x * 1024;
    int t = threadIdx.x;
    float4 v = *(const float4*)(z + base + t * 4);
    ushort4 h, l;
    h.x = bf16rne(v.x); l.x = bf16rne(v.x - bf16f(h.x));
    h.y = bf16rne(v.y); l.y = bf16rne(v.y - bf16f(h.y));
    h.z = bf16rne(v.z); l.z = bf16rne(v.z - bf16f(h.z));
    h.w = bf16rne(v.w); l.w = bf16rne(v.w - bf16f(h.w));
    *(ushort4*)(zhi + base + t * 4) = h;
    *(ushort4*)(zlo + base + t * 4) = l;
    int rowA = t >> 6, dA = (t & 63) * 4;
    *(float4*)&zs[rowA * 264 + dA] = v;
    __syncthreads();
    if (t < 64) {
        int rowL = t >> 4;
        int sub = t & 15;
        int hb = sub >> 3;
        int j = sub & 7;
        const float* a = zs + rowL * 264 + hb * 128 + j;
        float v0 = a[0];
        float c = __fmul_rn(v0, v0);
        #pragma unroll
        for (int i = 1; i < 16; ++i) {
            float w = a[8 * i];
            c = __fadd_rn(c, __fmul_rn(w, w));
        }
        float p;
        p = __shfl_xor(c, 1, 64); c = __fadd_rn(c, p);
        p = __shfl_xor(c, 2, 64); c = __fadd_rn(c, p);
        p = __shfl_xor(c, 4, 64); c = __fadd_rn(c, p);
        p = __shfl_xor(c, 8, 64); c = __fadd_rn(c, p);
        if (sub == 0) szn[blockIdx.x * 4 + rowL] = c;
    }
}

// MFMA distance-argmin. 256 blocks x 4 waves x 32 rows/wave (two 16-row
// A-fragment groups share every B fragment: 32 ds_read_b128 -> 96 MFMA per
// tile, halving per-CU LDS-read volume vs 16 rows/wave). e-splits staged per
// 32-code tile via global_load_lds, double-buffered, T2 XOR-swizzle applied
// as inverse-swizzled SOURCE + swizzled READ (linear LDS dest, rule 21).
// Per-(row,code) arithmetic is bit-identical to the round-6 kernel.
__global__ __launch_bounds__(256, 1) void vq_mfma(const u16* __restrict__ zhi,
                                                  const u16* __restrict__ zlo,
                                                  const u16* __restrict__ ehi,
                                                  const u16* __restrict__ elo,
                                                  const float* __restrict__ sen,
                                                  float* __restrict__ idx_out,
                                                  unsigned* __restrict__ count,
                                                  unsigned* __restrict__ worklist) {
    __shared__ char lds[2][32768];   // per buffer: [0,16K) ehi tile, [16K,32K) elo tile
    const int tid = threadIdx.x;
    const int wid = tid >> 6;        // 0..3
    const int lane = tid & 63;
    const int col16 = lane & 15;
    const int koct = lane >> 4;
    const int s3 = col16 & 7;
    const int rowbase = blockIdx.x * 128 + wid * 32;

    // A fragments: 2 row-groups x 8 d-chunks x {hi,lo} (~128 VGPR; bounds(256,1)
    // gives the allocator 512 so nothing spills)
    bf16x8 zh[2][8], zl[2][8];
    #pragma unroll
    for (int g = 0; g < 2; ++g) {
        const u16* ph = zhi + (size_t)(rowbase + g * 16 + col16) * DIM + koct * 8;
        const u16* pl = zlo + (size_t)(rowbase + g * 16 + col16) * DIM + koct * 8;
        #pragma unroll
        for (int dc = 0; dc < 8; ++dc) {
            zh[g][dc] = *(const bf16x8*)(ph + dc * 32);
            zl[g][dc] = *(const bf16x8*)(pl + dc * 32);
        }
    }

    float best[2][4], second[2][4];
    int besti[2][4];
    #pragma unroll
    for (int g = 0; g < 2; ++g)
        #pragma unroll
        for (int r = 0; r < 4; ++r) {
            best[g][r] = 3.4e38f; second[g][r] = 3.4e38f; besti[g][r] = 0;
        }

    // stage tile tt into buffer b: 2048 chunks of 16B ([0,1024)=ehi, rest=elo)
    auto STAGE = [&](int tt, int b) {
        #pragma unroll
        for (int r = 0; r < 8; ++r) {
            int p = r * 256 + tid;
            int q = p & 1023;
            int src = q ^ ((q >> 5) & 7);          // inverse swizzle (involution)
            const char* sp = ((p >> 10) ? (const char*)elo : (const char*)ehi)
                             + (size_t)tt * 16384 + src * 16;
            gload_lds16(sp, &lds[b][p * 16]);
        }
    };

    STAGE(0, 0);
    __syncthreads();

    for (int tt = 0; tt < NT; ++tt) {
        if (tt + 1 < NT) STAGE(tt + 1, (tt + 1) & 1);
        const char* bb = lds[tt & 1];
        #pragma unroll
        for (int ct = 0; ct < 2; ++ct) {
            const int lc = ct * 16 + col16;
            const int c = tt * TC + lc;
            const float sh = 0.5f * sen[c];
            const int rbase = lc * 512;
            f32x4 aHH[2], aLH[2], aHL[2];
            #pragma unroll
            for (int g = 0; g < 2; ++g) {
                aHH[g] = (f32x4){0.f, 0.f, 0.f, 0.f};
                aLH[g] = (f32x4){0.f, 0.f, 0.f, 0.f};
                aHL[g] = (f32x4){0.f, 0.f, 0.f, 0.f};
            }
            #pragma unroll
            for (int dc = 0; dc < 8; ++dc) {
                int off = ((dc * 4 + koct) ^ s3) * 16;   // swizzled read
                bf16x8 bh = *(const bf16x8*)(bb + rbase + off);
                bf16x8 bl = *(const bf16x8*)(bb + 16384 + rbase + off);
                #pragma unroll
                for (int g = 0; g < 2; ++g) {
                    aHH[g] = __builtin_amdgcn_mfma_f32_16x16x32_bf16(zh[g][dc], bh, aHH[g], 0, 0, 0);
                    aLH[g] = __builtin_amdgcn_mfma_f32_16x16x32_bf16(zl[g][dc], bh, aLH[g], 0, 0, 0);
                    aHL[g] = __builtin_amdgcn_mfma_f32_16x16x32_bf16(zh[g][dc], bl, aHL[g], 0, 0, 0);
                }
            }
            #pragma unroll
            for (int g = 0; g < 2; ++g)
                #pragma unroll
                for (int r = 0; r < 4; ++r) {
                    float s = sh + (aHH[g][r] + (aLH[g][r] + aHL[g][r]));
                    if (s < best[g][r]) { second[g][r] = best[g][r]; best[g][r] = s; besti[g][r] = c; }
                    else if (s < second[g][r]) { second[g][r] = s; }
                }
        }
        __syncthreads();   // drains global_load_lds + protects buffers
    }

    #pragma unroll
    for (int g = 0; g < 2; ++g)
        #pragma unroll
        for (int r = 0; r < 4; ++r) {
            float v1 = best[g][r], v2 = second[g][r];
            int i1 = besti[g][r];
            #pragma unroll
            for (int m = 1; m < 16; m <<= 1) {
                float ov1 = __shfl_xor(v1, m, 64);
                int   oi1 = __shfl_xor(i1, m, 64);
                float ov2 = __shfl_xor(v2, m, 64);
                if (ov1 < v1 || (ov1 == v1 && oi1 < i1)) {
                    v2 = fminf(v1, ov2); v1 = ov1; i1 = oi1;
                } else {
                    v2 = fminf(v2, ov1);
                }
            }
            if (col16 == 0) {
                int row = rowbase + g * 16 + koct * 4 + r;
                idx_out[row] = (float)i1;
                if (v2 - v1 < 0.5f * THETA) {   // acc is score/2
                    unsigned slot = atomicAdd(count, 1u);
                    worklist[slot] = (unsigned)row;
                }
            }
        }
}

// np-fp32 emulation for ambiguous rows. Wave-per-row (1024 concurrent waves,
// no barriers): lane owns 16 codes, d-chunk-outer loop keeps z in registers
// and gives 16 independent fp64 chains. dref formula identical to the
// version that passes: dref = fl(fl(sz+sen_k) - 2*fl32(dot64_k)).
__global__ __launch_bounds__(256) void vq_fixup(const float* __restrict__ z,
                                                const float* __restrict__ cb,
                                                const float* __restrict__ sen,
                                                const float* __restrict__ szn,
                                                const unsigned* __restrict__ count,
                                                const unsigned* __restrict__ worklist,
                                                float* __restrict__ idx_out) {
    int wave = blockIdx.x * 4 + (threadIdx.x >> 6);
    int lane = threadIdx.x & 63;
    int n = (int)*count;
    for (int w = wave; w < n; w += 1024) {
        int row = (int)worklist[w];
        float sz = szn[row];
        const float* zr = z + (size_t)row * DIM;
        const float* eb = cb + (size_t)(lane * 16) * DIM;
        double acc[16];
        #pragma unroll
        for (int j = 0; j < 16; ++j) acc[j] = 0.0;
        for (int ch = 0; ch < 16; ++ch) {
            const float* zp = zr + ch * 16;
            float4 z0 = *(const float4*)(zp + 0);
            float4 z1 = *(const float4*)(zp + 4);
            float4 z2 = *(const float4*)(zp + 8);
            float4 z3 = *(const float4*)(zp + 12);
            #pragma unroll
            for (int j = 0; j < 16; ++j) {
                const float* e = eb + j * DIM + ch * 16;
                float4 e0 = *(const float4*)(e + 0);
                float4 e1 = *(const float4*)(e + 4);
                float4 e2 = *(const float4*)(e + 8);
                float4 e3 = *(const float4*)(e + 12);
                acc[j] += (double)e0.x * z0.x + (double)e0.y * z0.y
                        + (double)e0.z * z0.z + (double)e0.w * z0.w
                        + (double)e1.x * z1.x + (double)e1.y * z1.y
                        + (double)e1.z * z1.z + (double)e1.w * z1.w
                        + (double)e2.x * z2.x + (double)e2.y * z2.y
                        + (double)e2.z * z2.z + (double)e2.w * z2.w
                        + (double)e3.x * z3.x + (double)e3.y * z3.y
                        + (double)e3.z * z3.z + (double)e3.w * z3.w;
            }
        }
        float bv = 3.4e38f;
        int bi = 0;
        #pragma unroll
        for (int j = 0; j < 16; ++j) {          // ascending c within lane
            int c = lane * 16 + j;
            float dotx = (float)acc[j];
            float A = __fadd_rn(sz, sen[c]);
            float dref = __fmaf_rn(-2.0f, dotx, A);
            if (dref < bv) { bv = dref; bi = c; }
        }
        #pragma unroll
        for (int m = 1; m < 64; m <<= 1) {      // 64-lane lex-min butterfly
            float ov = __shfl_xor(bv, m, 64);
            int oi = __shfl_xor(bi, m, 64);
            if (ov < bv || (ov == bv && oi < bi)) { bv = ov; bi = oi; }
        }
        if (lane == 0) idx_out[row] = (float)bi;
    }
}

// quantized_ste = z + (q - z); commitment loss; histogram from final idx
__global__ __launch_bounds__(256) void vq_gather(const float* __restrict__ z,
                                                 const float* __restrict__ cb,
                                                 const float* __restrict__ idxf,
                                                 float* __restrict__ qout,
                                                 double* __restrict__ loss_acc,
                                                 unsigned* __restrict__ hist) {
    int gid = blockIdx.x * 256 + threadIdx.x;
    int row = gid >> 6, c4 = gid & 63;
    int idx = (int)idxf[row];
    if (c4 == 0) atomicAdd(&hist[idx], 1u);
    float4 zv = *(const float4*)(z + (size_t)row * DIM + c4 * 4);
    float4 qv = *(const float4*)(cb + (size_t)idx * DIM + c4 * 4);
    float dx = qv.x - zv.x, dy = qv.y - zv.y, dz = qv.z - zv.z, dw = qv.w - zv.w;
    float4 o;
    o.x = zv.x + dx; o.y = zv.y + dy; o.z = zv.z + dz; o.w = zv.w + dw;
    *(float4*)(qout + (size_t)row * DIM + c4 * 4) = o;
    float ls = dx * dx + dy * dy + dz * dz + dw * dw;
    #pragma unroll
    for (int off = 32; off; off >>= 1) ls += __shfl_down(ls, off, 64);
    __shared__ float wsum[4];
    int lane = threadIdx.x & 63, wv = threadIdx.x >> 6;
    if (lane == 0) wsum[wv] = ls;
    __syncthreads();
    if (threadIdx.x == 0)
        atomicAdd(loss_acc, (double)(wsum[0] + wsum[1] + wsum[2] + wsum[3]));
}

__global__ __launch_bounds__(1024) void vq_finalize(const unsigned* __restrict__ hist,
                                                    const double* __restrict__ loss_acc,
                                                    float* __restrict__ out) {
    __shared__ float red[1024];
    int t = threadIdx.x;
    float p = (float)hist[t] * (1.0f / (float)N_ROWS);
    red[t] = p * logf(p + 1e-10f);
    __syncthreads();
    for (int s = 512; s; s >>= 1) {
        if (t < s) red[t] += red[t + s];
        __syncthreads();
    }
    if (t == 0) {
        out[ZERO_OFF] = 0.0f;
        out[LOSS_OFF] = (float)(0.25 * (*loss_acc) / (double)Q_N);
        out[PERP_OFF] = expf(-red[0]);
    }
}

extern "C" void kernel_launch(void* const* d_in, const int* in_sizes, int n_in,
                              void* d_out, int out_size, void* d_ws, size_t ws_size,
                              hipStream_t stream) {
    const float* z = (const float*)d_in[0];
    const float* cb = (const float*)d_in[1];
    float* out = (float*)d_out;

    float* sen = (float*)d_ws;
    unsigned* hist = (unsigned*)((char*)d_ws + 4096);
    double* loss_acc = (double*)((char*)d_ws + 8192);
    unsigned* count = (unsigned*)((char*)d_ws + 8200);
    float* szn = (float*)((char*)d_ws + 8448);
    unsigned* worklist = (unsigned*)((char*)d_ws + 139520);
    u16* ehi = (u16*)((char*)d_ws + 270592);
    u16* elo = (u16*)((char*)d_ws + 794880);

    u16* zhi = (u16*)d_out;
    u16* zlo = (u16*)d_out + Q_N;

    vq_prep_cb<<<KCODES / 4, 256, 0, stream>>>(cb, sen, ehi, elo, hist, loss_acc, count);
    vq_prep_z<<<N_ROWS / 4, 256, 0, stream>>>(z, zhi, zlo, szn);
    vq_mfma<<<N_ROWS / 128, 256, 0, stream>>>(zhi, zlo, ehi, elo, sen,
                                              out + IDX_OFF, count, worklist);
    vq_fixup<<<256, 256, 0, stream>>>(z, cb, sen, szn, count, worklist, out + IDX_OFF);
    vq_gather<<<(N_ROWS * (DIM / 4)) / 256, 256, 0, stream>>>(z, cb, out + IDX_OFF, out, loss_acc, hist);
    vq_finalize<<<1, 1024, 0, stream>>>(hist, loss_acc, out);
}

// Round 8
// 313.581 us; speedup vs baseline: 1.1512x; 1.1512x over previous
//
#include <hip/hip_runtime.h>

#define N_ROWS 32768
#define DIM 256
#define KCODES 1024

#define Q_N (N_ROWS * DIM)          // 8388608
#define IDX_OFF Q_N                 // 8388608
#define ZERO_OFF (Q_N + N_ROWS)     // 8421376
#define LOSS_OFF (ZERO_OFF + 1)
#define PERP_OFF (ZERO_OFF + 2)

// Safe ambiguity margin (score units): np's d-quantization can only reorder
// codes whose exact scores differ by < 2*ulp(d~256)=6.1e-5; our fast-path
// score error is <~5e-6. 8e-5 covers both with slack.
#define THETA 8.0e-5f

#define TC 32                 // codes per LDS tile (mfma)
#define NT (KCODES / TC)      // 32 tiles

#define FIX_BLOCKS 128
#define FIX_R 4               // worklist rows per sweep per block

typedef __attribute__((ext_vector_type(8))) short bf16x8;
typedef __attribute__((ext_vector_type(4))) float f32x4;
typedef unsigned short u16;

// ws layout (bytes):
//   [0, 4096)          sen float[K]
//   [4096, 8192)       hist uint[K]
//   [8192, 8200)       double loss_acc
//   [8200, 8204)       uint ambig_count
//   [8448, 139520)     szn float[32768]  (numpy-pairwise ||z||^2)
//   [139520, 270592)   uint worklist[32768]
//   [270592, 794880)   ehi u16[262144]   (bf16 of -e)
//   [794880, 1319168)  elo u16[262144]   (bf16 of (-e) - ehi)
// zhi/zlo live in d_out's q region until vq_gather overwrites it.

__device__ inline u16 bf16rne(float f) {
    unsigned u = __float_as_uint(f);
    return (u16)((u + 0x7FFFu + ((u >> 16) & 1u)) >> 16);
}
__device__ inline float bf16f(u16 h) { return __uint_as_float((unsigned)h << 16); }

typedef __attribute__((address_space(3))) unsigned int as3_uint;
typedef __attribute__((address_space(1))) const unsigned int as1_uint;
__device__ inline void gload_lds16(const void* g, void* l) {
    __builtin_amdgcn_global_load_lds((as1_uint*)g, (as3_uint*)l, 16, 0, 0);
}

// fused: init(hist/loss/count) + accurate ||e||^2 + negated bf16 hi/lo splits.
__global__ __launch_bounds__(256) void vq_prep_cb(const float* __restrict__ cb,
                                                  float* __restrict__ sen,
                                                  u16* __restrict__ ehi,
                                                  u16* __restrict__ elo,
                                                  unsigned* __restrict__ hist,
                                                  double* __restrict__ loss_acc,
                                                  unsigned* __restrict__ count) {
    int b = blockIdx.x, t = threadIdx.x;
    if (b < 4) {
        hist[b * 256 + t] = 0u;
        if (b == 0 && t == 0) { *loss_acc = 0.0; *count = 0u; }
    }
    int code = b * 4 + (t >> 6);
    int lane = t & 63;
    size_t eoff = (size_t)code * DIM + lane * 4;
    float4 v = *(const float4*)(cb + eoff);
    double s = (double)v.x * v.x + (double)v.y * v.y + (double)v.z * v.z + (double)v.w * v.w;
    #pragma unroll
    for (int off = 32; off; off >>= 1) s += __shfl_down(s, off, 64);
    if (lane == 0) sen[code] = (float)s;
    v.x = -v.x; v.y = -v.y; v.z = -v.z; v.w = -v.w;
    ushort4 h, l;
    h.x = bf16rne(v.x); l.x = bf16rne(v.x - bf16f(h.x));
    h.y = bf16rne(v.y); l.y = bf16rne(v.y - bf16f(h.y));
    h.z = bf16rne(v.z); l.z = bf16rne(v.z - bf16f(h.z));
    h.w = bf16rne(v.w); l.w = bf16rne(v.w - bf16f(h.w));
    *(ushort4*)(ehi + eoff) = h;
    *(ushort4*)(elo + eoff) = l;
}

// fused: z -> bf16 hi/lo splits + numpy-pairwise-exact ||z||^2.
__global__ __launch_bounds__(256) void vq_prep_z(const float* __restrict__ z,
                                                 u16* __restrict__ zhi,
                                                 u16* __restrict__ zlo,
                                                 float* __restrict__ szn) {
    __shared__ float zs[4 * 264];
    size_t base = (size_t)blockIdx.x * 1024;
    int t = threadIdx.x;
    float4 v = *(const float4*)(z + base + t * 4);
    ushort4 h, l;
    h.x = bf16rne(v.x); l.x = bf16rne(v.x - bf16f(h.x));
    h.y = bf16rne(v.y); l.y = bf16rne(v.y - bf16f(h.y));
    h.z = bf16rne(v.z); l.z = bf16rne(v.z - bf16f(h.z));
    h.w = bf16rne(v.w); l.w = bf16rne(v.w - bf16f(h.w));
    *(ushort4*)(zhi + base + t * 4) = h;
    *(ushort4*)(zlo + base + t * 4) = l;
    int rowA = t >> 6, dA = (t & 63) * 4;
    *(float4*)&zs[rowA * 264 + dA] = v;
    __syncthreads();
    if (t < 64) {
        int rowL = t >> 4;
        int sub = t & 15;
        int hb = sub >> 3;
        int j = sub & 7;
        const float* a = zs + rowL * 264 + hb * 128 + j;
        float v0 = a[0];
        float c = __fmul_rn(v0, v0);
        #pragma unroll
        for (int i = 1; i < 16; ++i) {
            float w = a[8 * i];
            c = __fadd_rn(c, __fmul_rn(w, w));
        }
        float p;
        p = __shfl_xor(c, 1, 64); c = __fadd_rn(c, p);
        p = __shfl_xor(c, 2, 64); c = __fadd_rn(c, p);
        p = __shfl_xor(c, 4, 64); c = __fadd_rn(c, p);
        p = __shfl_xor(c, 8, 64); c = __fadd_rn(c, p);
        if (sub == 0) szn[blockIdx.x * 4 + rowL] = c;
    }
}

// MFMA distance-argmin (unchanged from round 7 — counters pending).
__global__ __launch_bounds__(256, 1) void vq_mfma(const u16* __restrict__ zhi,
                                                  const u16* __restrict__ zlo,
                                                  const u16* __restrict__ ehi,
                                                  const u16* __restrict__ elo,
                                                  const float* __restrict__ sen,
                                                  float* __restrict__ idx_out,
                                                  unsigned* __restrict__ count,
                                                  unsigned* __restrict__ worklist) {
    __shared__ char lds[2][32768];   // per buffer: [0,16K) ehi tile, [16K,32K) elo tile
    const int tid = threadIdx.x;
    const int wid = tid >> 6;
    const int lane = tid & 63;
    const int col16 = lane & 15;
    const int koct = lane >> 4;
    const int s3 = col16 & 7;
    const int rowbase = blockIdx.x * 128 + wid * 32;

    bf16x8 zh[2][8], zl[2][8];
    #pragma unroll
    for (int g = 0; g < 2; ++g) {
        const u16* ph = zhi + (size_t)(rowbase + g * 16 + col16) * DIM + koct * 8;
        const u16* pl = zlo + (size_t)(rowbase + g * 16 + col16) * DIM + koct * 8;
        #pragma unroll
        for (int dc = 0; dc < 8; ++dc) {
            zh[g][dc] = *(const bf16x8*)(ph + dc * 32);
            zl[g][dc] = *(const bf16x8*)(pl + dc * 32);
        }
    }

    float best[2][4], second[2][4];
    int besti[2][4];
    #pragma unroll
    for (int g = 0; g < 2; ++g)
        #pragma unroll
        for (int r = 0; r < 4; ++r) {
            best[g][r] = 3.4e38f; second[g][r] = 3.4e38f; besti[g][r] = 0;
        }

    auto STAGE = [&](int tt, int b) {
        #pragma unroll
        for (int r = 0; r < 8; ++r) {
            int p = r * 256 + tid;
            int q = p & 1023;
            int src = q ^ ((q >> 5) & 7);          // inverse swizzle (involution)
            const char* sp = ((p >> 10) ? (const char*)elo : (const char*)ehi)
                             + (size_t)tt * 16384 + src * 16;
            gload_lds16(sp, &lds[b][p * 16]);
        }
    };

    STAGE(0, 0);
    __syncthreads();

    for (int tt = 0; tt < NT; ++tt) {
        if (tt + 1 < NT) STAGE(tt + 1, (tt + 1) & 1);
        const char* bb = lds[tt & 1];
        #pragma unroll
        for (int ct = 0; ct < 2; ++ct) {
            const int lc = ct * 16 + col16;
            const int c = tt * TC + lc;
            const float sh = 0.5f * sen[c];
            const int rbase = lc * 512;
            f32x4 aHH[2], aLH[2], aHL[2];
            #pragma unroll
            for (int g = 0; g < 2; ++g) {
                aHH[g] = (f32x4){0.f, 0.f, 0.f, 0.f};
                aLH[g] = (f32x4){0.f, 0.f, 0.f, 0.f};
                aHL[g] = (f32x4){0.f, 0.f, 0.f, 0.f};
            }
            #pragma unroll
            for (int dc = 0; dc < 8; ++dc) {
                int off = ((dc * 4 + koct) ^ s3) * 16;   // swizzled read
                bf16x8 bh = *(const bf16x8*)(bb + rbase + off);
                bf16x8 bl = *(const bf16x8*)(bb + 16384 + rbase + off);
                #pragma unroll
                for (int g = 0; g < 2; ++g) {
                    aHH[g] = __builtin_amdgcn_mfma_f32_16x16x32_bf16(zh[g][dc], bh, aHH[g], 0, 0, 0);
                    aLH[g] = __builtin_amdgcn_mfma_f32_16x16x32_bf16(zl[g][dc], bh, aLH[g], 0, 0, 0);
                    aHL[g] = __builtin_amdgcn_mfma_f32_16x16x32_bf16(zh[g][dc], bl, aHL[g], 0, 0, 0);
                }
            }
            #pragma unroll
            for (int g = 0; g < 2; ++g)
                #pragma unroll
                for (int r = 0; r < 4; ++r) {
                    float s = sh + (aHH[g][r] + (aLH[g][r] + aHL[g][r]));
                    if (s < best[g][r]) { second[g][r] = best[g][r]; best[g][r] = s; besti[g][r] = c; }
                    else if (s < second[g][r]) { second[g][r] = s; }
                }
        }
        __syncthreads();
    }

    #pragma unroll
    for (int g = 0; g < 2; ++g)
        #pragma unroll
        for (int r = 0; r < 4; ++r) {
            float v1 = best[g][r], v2 = second[g][r];
            int i1 = besti[g][r];
            #pragma unroll
            for (int m = 1; m < 16; m <<= 1) {
                float ov1 = __shfl_xor(v1, m, 64);
                int   oi1 = __shfl_xor(i1, m, 64);
                float ov2 = __shfl_xor(v2, m, 64);
                if (ov1 < v1 || (ov1 == v1 && oi1 < i1)) {
                    v2 = fminf(v1, ov2); v1 = ov1; i1 = oi1;
                } else {
                    v2 = fminf(v2, ov1);
                }
            }
            if (col16 == 0) {
                int row = rowbase + g * 16 + koct * 4 + r;
                idx_out[row] = (float)i1;
                if (v2 - v1 < 0.5f * THETA) {   // acc is score/2
                    unsigned slot = atomicAdd(count, 1u);
                    worklist[slot] = (unsigned)row;
                }
            }
        }
}

// np-fp32 emulation for ambiguous rows — LDS-tiled, coalesced.
// 128 blocks x 256 threads; block takes up to 4 rows per sweep; codebook
// iterated in 32-code x 256-dim fp32 tiles staged coalesced into LDS and
// shared by all rows of the sweep. Thread = (code c5, dim-chunk ch); fp64
// partial over 32 dims (start rotated by c5 -> conflict-free LDS reads);
// per-code chunk partials reduced in fixed order; dref formula bit-identical
// to the passing version: dref = fl(fl(sz+sen_k) - 2*fl32(dot64_k)).
__global__ __launch_bounds__(256) void vq_fixup(const float* __restrict__ z,
                                                const float* __restrict__ cb,
                                                const float* __restrict__ sen,
                                                const float* __restrict__ szn,
                                                const unsigned* __restrict__ count,
                                                const unsigned* __restrict__ worklist,
                                                float* __restrict__ idx_out) {
    __shared__ float et[TC * DIM];          // 32 KB e-tile [code][dim]
    __shared__ float zr[FIX_R][DIM];        // 4 KB
    __shared__ double red[FIX_R][32][9];    // padded: chunk partials
    __shared__ float bestv[FIX_R][32];
    __shared__ int   bestc[FIX_R][32];
    __shared__ int   rows_s[FIX_R];
    __shared__ float szn_s[FIX_R];

    const int t = threadIdx.x;
    const int c5 = t & 31;                  // code within tile
    const int ch = t >> 5;                  // dim chunk (0..7)
    const int n = (int)*count;

    for (int base = blockIdx.x * FIX_R; base < n; base += FIX_BLOCKS * FIX_R) {
        const int R = min(FIX_R, n - base);
        if (t < R) {
            int row = (int)worklist[base + t];
            rows_s[t] = row;
            szn_s[t] = szn[row];
        }
        if (t < 32 * FIX_R) {
            bestv[t >> 5][t & 31] = 3.4e38f;
            bestc[t >> 5][t & 31] = 0x7fffffff;
        }
        __syncthreads();                    // rows_s visible for zr loads
        for (int r = 0; r < R; ++r)
            zr[r][t] = z[(size_t)rows_s[r] * DIM + t];

        for (int tt = 0; tt < NT; ++tt) {
            // stage e-tile coalesced: 2048 float4 / 256 threads = 8 each
            const float4* src = (const float4*)(cb + (size_t)tt * TC * DIM);
            #pragma unroll
            for (int i = 0; i < 8; ++i)
                ((float4*)et)[i * 256 + t] = src[i * 256 + t];
            __syncthreads();

            const float* ez = &et[c5 * DIM + ch * 32];
            #pragma unroll 2
            for (int r = 0; r < R; ++r) {
                const float* zz = &zr[r][ch * 32];
                double acc = 0.0;
                #pragma unroll
                for (int j = 0; j < 32; ++j) {
                    int d = (j + c5) & 31;  // rotation: conflict-free LDS reads
                    acc += (double)ez[d] * (double)zz[d];
                }
                red[r][c5][ch] = acc;
            }
            __syncthreads();

            if (t < 32 * R) {
                int r = t >> 5;
                double s = ((red[r][c5][0] + red[r][c5][1])
                          + (red[r][c5][2] + red[r][c5][3]))
                         + ((red[r][c5][4] + red[r][c5][5])
                          + (red[r][c5][6] + red[r][c5][7]));
                int c = tt * TC + c5;
                float dotx = (float)s;
                float A = __fadd_rn(szn_s[r], sen[c]);
                float dref = __fmaf_rn(-2.0f, dotx, A);
                if (dref < bestv[r][c5]) {  // strict <: lowest tile wins ties
                    bestv[r][c5] = dref;
                    bestc[r][c5] = c;
                }
            }
            __syncthreads();                // update done before next stage/compute
        }

        if (t < 32 * R) {
            int r = t >> 5;
            float bv = bestv[r][c5];
            int bi = bestc[r][c5];
            #pragma unroll
            for (int m = 1; m < 32; m <<= 1) {   // lex-min over the 32-lane group
                float ov = __shfl_xor(bv, m, 64);
                int oi = __shfl_xor(bi, m, 64);
                if (ov < bv || (ov == bv && oi < bi)) { bv = ov; bi = oi; }
            }
            if (c5 == 0) idx_out[rows_s[r]] = (float)bi;
        }
        __syncthreads();                    // protect rows_s/zr/bestv for next sweep
    }
}

// quantized_ste = z + (q - z); commitment loss; histogram from final idx
__global__ __launch_bounds__(256) void vq_gather(const float* __restrict__ z,
                                                 const float* __restrict__ cb,
                                                 const float* __restrict__ idxf,
                                                 float* __restrict__ qout,
                                                 double* __restrict__ loss_acc,
                                                 unsigned* __restrict__ hist) {
    int gid = blockIdx.x * 256 + threadIdx.x;
    int row = gid >> 6, c4 = gid & 63;
    int idx = (int)idxf[row];
    if (c4 == 0) atomicAdd(&hist[idx], 1u);
    float4 zv = *(const float4*)(z + (size_t)row * DIM + c4 * 4);
    float4 qv = *(const float4*)(cb + (size_t)idx * DIM + c4 * 4);
    float dx = qv.x - zv.x, dy = qv.y - zv.y, dz = qv.z - zv.z, dw = qv.w - zv.w;
    float4 o;
    o.x = zv.x + dx; o.y = zv.y + dy; o.z = zv.z + dz; o.w = zv.w + dw;
    *(float4*)(qout + (size_t)row * DIM + c4 * 4) = o;
    float ls = dx * dx + dy * dy + dz * dz + dw * dw;
    #pragma unroll
    for (int off = 32; off; off >>= 1) ls += __shfl_down(ls, off, 64);
    __shared__ float wsum[4];
    int lane = threadIdx.x & 63, wv = threadIdx.x >> 6;
    if (lane == 0) wsum[wv] = ls;
    __syncthreads();
    if (threadIdx.x == 0)
        atomicAdd(loss_acc, (double)(wsum[0] + wsum[1] + wsum[2] + wsum[3]));
}

__global__ __launch_bounds__(1024) void vq_finalize(const unsigned* __restrict__ hist,
                                                    const double* __restrict__ loss_acc,
                                                    float* __restrict__ out) {
    __shared__ float red[1024];
    int t = threadIdx.x;
    float p = (float)hist[t] * (1.0f / (float)N_ROWS);
    red[t] = p * logf(p + 1e-10f);
    __syncthreads();
    for (int s = 512; s; s >>= 1) {
        if (t < s) red[t] += red[t + s];
        __syncthreads();
    }
    if (t == 0) {
        out[ZERO_OFF] = 0.0f;
        out[LOSS_OFF] = (float)(0.25 * (*loss_acc) / (double)Q_N);
        out[PERP_OFF] = expf(-red[0]);
    }
}

extern "C" void kernel_launch(void* const* d_in, const int* in_sizes, int n_in,
                              void* d_out, int out_size, void* d_ws, size_t ws_size,
                              hipStream_t stream) {
    const float* z = (const float*)d_in[0];
    const float* cb = (const float*)d_in[1];
    float* out = (float*)d_out;

    float* sen = (float*)d_ws;
    unsigned* hist = (unsigned*)((char*)d_ws + 4096);
    double* loss_acc = (double*)((char*)d_ws + 8192);
    unsigned* count = (unsigned*)((char*)d_ws + 8200);
    float* szn = (float*)((char*)d_ws + 8448);
    unsigned* worklist = (unsigned*)((char*)d_ws + 139520);
    u16* ehi = (u16*)((char*)d_ws + 270592);
    u16* elo = (u16*)((char*)d_ws + 794880);

    u16* zhi = (u16*)d_out;
    u16* zlo = (u16*)d_out + Q_N;

    vq_prep_cb<<<KCODES / 4, 256, 0, stream>>>(cb, sen, ehi, elo, hist, loss_acc, count);
    vq_prep_z<<<N_ROWS / 4, 256, 0, stream>>>(z, zhi, zlo, szn);
    vq_mfma<<<N_ROWS / 128, 256, 0, stream>>>(zhi, zlo, ehi, elo, sen,
                                              out + IDX_OFF, count, worklist);
    vq_fixup<<<FIX_BLOCKS, 256, 0, stream>>>(z, cb, sen, szn, count, worklist, out + IDX_OFF);
    vq_gather<<<(N_ROWS * (DIM / 4)) / 256, 256, 0, stream>>>(z, cb, out + IDX_OFF, out, loss_acc, hist);
    vq_finalize<<<1, 1024, 0, stream>>>(hist, loss_acc, out);
}

// Round 9
// 259.161 us; speedup vs baseline: 1.3929x; 1.2100x over previous
//
#include <hip/hip_runtime.h>

#define N_ROWS 32768
#define DIM 256
#define KCODES 1024

#define Q_N (N_ROWS * DIM)          // 8388608
#define IDX_OFF Q_N                 // 8388608
#define ZERO_OFF (Q_N + N_ROWS)     // 8421376
#define LOSS_OFF (ZERO_OFF + 1)
#define PERP_OFF (ZERO_OFF + 2)

// Safe ambiguity margin (score units): np's d-quantization can only reorder
// codes whose exact scores differ by < 2*ulp(d~256)=6.1e-5; our fast-path
// score error is <~1e-5. 8e-5 covers both with slack.
#define THETA 8.0e-5f

#define TC 32                 // codes per LDS tile (mfma)
#define NT (KCODES / TC)      // 32 tiles

typedef __attribute__((ext_vector_type(8))) short bf16x8;
typedef __attribute__((ext_vector_type(4))) float f32x4;
typedef unsigned short u16;

// ws layout (bytes):
//   [0, 4096)            sen float[K]
//   [4096, 8192)         hist uint[K]
//   [8192, 8200)         double loss_acc
//   [8200, 8204)         uint pair_count
//   [8204, 8208)         uint full_count
//   [8448, 139520)       szn float[32768]   (numpy-pairwise ||z||^2)
//   [139520, 401664)     pairlist uint2[32768]  {row, c1<<16|c2}
//   [401664, 532736)     fulllist uint[32768]
//   [532736, 1057024)    ehi u16[262144]    (bf16 of -e)
//   [1057024, 1581312)   elo u16[262144]    (bf16 of (-e) - ehi)
// zhi/zlo live in d_out's q region until vq_gather overwrites it.

__device__ inline u16 bf16rne(float f) {
    unsigned u = __float_as_uint(f);
    return (u16)((u + 0x7FFFu + ((u >> 16) & 1u)) >> 16);
}
__device__ inline float bf16f(u16 h) { return __uint_as_float((unsigned)h << 16); }

__device__ inline bool lexless(float av, int ai, float bv, int bi) {
    return av < bv || (av == bv && ai < bi);
}

typedef __attribute__((address_space(3))) unsigned int as3_uint;
typedef __attribute__((address_space(1))) const unsigned int as1_uint;
__device__ inline void gload_lds16(const void* g, void* l) {
    __builtin_amdgcn_global_load_lds((as1_uint*)g, (as3_uint*)l, 16, 0, 0);
}

// fused: init(hist/loss/counters) + accurate ||e||^2 + negated bf16 hi/lo splits.
__global__ __launch_bounds__(256) void vq_prep_cb(const float* __restrict__ cb,
                                                  float* __restrict__ sen,
                                                  u16* __restrict__ ehi,
                                                  u16* __restrict__ elo,
                                                  unsigned* __restrict__ hist,
                                                  double* __restrict__ loss_acc,
                                                  unsigned* __restrict__ pcnt,
                                                  unsigned* __restrict__ fcnt) {
    int b = blockIdx.x, t = threadIdx.x;
    if (b < 4) {
        hist[b * 256 + t] = 0u;
        if (b == 0 && t == 0) { *loss_acc = 0.0; *pcnt = 0u; *fcnt = 0u; }
    }
    int code = b * 4 + (t >> 6);
    int lane = t & 63;
    size_t eoff = (size_t)code * DIM + lane * 4;
    float4 v = *(const float4*)(cb + eoff);
    double s = (double)v.x * v.x + (double)v.y * v.y + (double)v.z * v.z + (double)v.w * v.w;
    #pragma unroll
    for (int off = 32; off; off >>= 1) s += __shfl_down(s, off, 64);
    if (lane == 0) sen[code] = (float)s;
    v.x = -v.x; v.y = -v.y; v.z = -v.z; v.w = -v.w;
    ushort4 h, l;
    h.x = bf16rne(v.x); l.x = bf16rne(v.x - bf16f(h.x));
    h.y = bf16rne(v.y); l.y = bf16rne(v.y - bf16f(h.y));
    h.z = bf16rne(v.z); l.z = bf16rne(v.z - bf16f(h.z));
    h.w = bf16rne(v.w); l.w = bf16rne(v.w - bf16f(h.w));
    *(ushort4*)(ehi + eoff) = h;
    *(ushort4*)(elo + eoff) = l;
}

// fused: z -> bf16 hi/lo splits + numpy-pairwise-exact ||z||^2.
__global__ __launch_bounds__(256) void vq_prep_z(const float* __restrict__ z,
                                                 u16* __restrict__ zhi,
                                                 u16* __restrict__ zlo,
                                                 float* __restrict__ szn) {
    __shared__ float zs[4 * 264];
    size_t base = (size_t)blockIdx.x * 1024;
    int t = threadIdx.x;
    float4 v = *(const float4*)(z + base + t * 4);
    ushort4 h, l;
    h.x = bf16rne(v.x); l.x = bf16rne(v.x - bf16f(h.x));
    h.y = bf16rne(v.y); l.y = bf16rne(v.y - bf16f(h.y));
    h.z = bf16rne(v.z); l.z = bf16rne(v.z - bf16f(h.z));
    h.w = bf16rne(v.w); l.w = bf16rne(v.w - bf16f(h.w));
    *(ushort4*)(zhi + base + t * 4) = h;
    *(ushort4*)(zlo + base + t * 4) = l;
    int rowA = t >> 6, dA = (t & 63) * 4;
    *(float4*)&zs[rowA * 264 + dA] = v;
    __syncthreads();
    if (t < 64) {
        int rowL = t >> 4;
        int sub = t & 15;
        int hb = sub >> 3;
        int j = sub & 7;
        const float* a = zs + rowL * 264 + hb * 128 + j;
        float v0 = a[0];
        float c = __fmul_rn(v0, v0);
        #pragma unroll
        for (int i = 1; i < 16; ++i) {
            float w = a[8 * i];
            c = __fadd_rn(c, __fmul_rn(w, w));
        }
        float p;
        p = __shfl_xor(c, 1, 64); c = __fadd_rn(c, p);
        p = __shfl_xor(c, 2, 64); c = __fadd_rn(c, p);
        p = __shfl_xor(c, 4, 64); c = __fadd_rn(c, p);
        p = __shfl_xor(c, 8, 64); c = __fadd_rn(c, p);
        if (sub == 0) szn[blockIdx.x * 4 + rowL] = c;
    }
}

// MFMA distance-argmin. 512 blocks x 4 waves x 16 rows/wave (2 blocks/CU:
// 2x64KB LDS <= 160KB, 2 waves/SIMD -> barrier/latency overlap across blocks).
// e-splits staged per 32-code tile via global_load_lds, double-buffered,
// T2 XOR-swizzle as inverse-swizzled SOURCE + swizzled READ (rule 21).
// Tracks top-3 per row; emits pairlist (2 candidates) or fulllist (>=3).
__global__ __launch_bounds__(256, 2) void vq_mfma(const u16* __restrict__ zhi,
                                                  const u16* __restrict__ zlo,
                                                  const u16* __restrict__ ehi,
                                                  const u16* __restrict__ elo,
                                                  const float* __restrict__ sen,
                                                  float* __restrict__ idx_out,
                                                  unsigned* __restrict__ pcnt,
                                                  uint2* __restrict__ pairlist,
                                                  unsigned* __restrict__ fcnt,
                                                  unsigned* __restrict__ fulllist) {
    __shared__ char lds[2][32768];   // per buffer: [0,16K) ehi tile, [16K,32K) elo tile
    const int tid = threadIdx.x;
    const int wid = tid >> 6;
    const int lane = tid & 63;
    const int col16 = lane & 15;
    const int koct = lane >> 4;
    const int s3 = col16 & 7;
    const int rowbase = blockIdx.x * 64 + wid * 16;

    bf16x8 zh[8], zl[8];
    {
        const u16* ph = zhi + (size_t)(rowbase + col16) * DIM + koct * 8;
        const u16* pl = zlo + (size_t)(rowbase + col16) * DIM + koct * 8;
        #pragma unroll
        for (int dc = 0; dc < 8; ++dc) {
            zh[dc] = *(const bf16x8*)(ph + dc * 32);
            zl[dc] = *(const bf16x8*)(pl + dc * 32);
        }
    }

    float v1[4], v2[4], v3[4];
    int i1[4], i2[4], i3[4];
    #pragma unroll
    for (int r = 0; r < 4; ++r) {
        v1[r] = v2[r] = v3[r] = 3.4e38f;
        i1[r] = i2[r] = i3[r] = 0x7fffffff;
    }

    auto STAGE = [&](int tt, int b) {
        #pragma unroll
        for (int r = 0; r < 8; ++r) {
            int p = r * 256 + tid;
            int q = p & 1023;
            int src = q ^ ((q >> 5) & 7);          // inverse swizzle (involution)
            const char* sp = ((p >> 10) ? (const char*)elo : (const char*)ehi)
                             + (size_t)tt * 16384 + src * 16;
            gload_lds16(sp, &lds[b][p * 16]);
        }
    };

    STAGE(0, 0);
    __syncthreads();

    for (int tt = 0; tt < NT; ++tt) {
        if (tt + 1 < NT) STAGE(tt + 1, (tt + 1) & 1);
        const char* bb = lds[tt & 1];
        #pragma unroll
        for (int ct = 0; ct < 2; ++ct) {
            const int lc = ct * 16 + col16;
            const int c = tt * TC + lc;
            const float sh = 0.5f * sen[c];
            const int rbase = lc * 512;
            f32x4 aHH = {0.f, 0.f, 0.f, 0.f};
            f32x4 aLH = {0.f, 0.f, 0.f, 0.f};
            f32x4 aHL = {0.f, 0.f, 0.f, 0.f};
            #pragma unroll
            for (int dc = 0; dc < 8; ++dc) {
                int off = ((dc * 4 + koct) ^ s3) * 16;   // swizzled read
                bf16x8 bh = *(const bf16x8*)(bb + rbase + off);
                bf16x8 bl = *(const bf16x8*)(bb + 16384 + rbase + off);
                aHH = __builtin_amdgcn_mfma_f32_16x16x32_bf16(zh[dc], bh, aHH, 0, 0, 0);
                aLH = __builtin_amdgcn_mfma_f32_16x16x32_bf16(zl[dc], bh, aLH, 0, 0, 0);
                aHL = __builtin_amdgcn_mfma_f32_16x16x32_bf16(zh[dc], bl, aHL, 0, 0, 0);
            }
            #pragma unroll
            for (int r = 0; r < 4; ++r) {
                float s = sh + (aHH[r] + (aLH[r] + aHL[r]));
                if (s < v1[r]) {
                    v3[r] = v2[r]; i3[r] = i2[r];
                    v2[r] = v1[r]; i2[r] = i1[r];
                    v1[r] = s; i1[r] = c;
                } else if (s < v2[r]) {
                    v3[r] = v2[r]; i3[r] = i2[r];
                    v2[r] = s; i2[r] = c;
                } else if (s < v3[r]) {
                    v3[r] = s; i3[r] = c;
                }
            }
        }
        __syncthreads();
    }

    #pragma unroll
    for (int r = 0; r < 4; ++r) {
        float a1 = v1[r], a2 = v2[r], a3 = v3[r];
        int b1 = i1[r], b2 = i2[r], b3 = i3[r];
        #pragma unroll
        for (int m = 1; m < 16; m <<= 1) {
            float o1 = __shfl_xor(a1, m, 64), o2 = __shfl_xor(a2, m, 64), o3 = __shfl_xor(a3, m, 64);
            int p1 = __shfl_xor(b1, m, 64), p2 = __shfl_xor(b2, m, 64), p3 = __shfl_xor(b3, m, 64);
            // insert o1,o2,o3 into sorted (a1..a3) [lex order, index-tiebreak]
            #pragma unroll
            for (int k = 0; k < 3; ++k) {
                float ov = (k == 0) ? o1 : (k == 1) ? o2 : o3;
                int oi = (k == 0) ? p1 : (k == 1) ? p2 : p3;
                if (lexless(ov, oi, a1, b1)) {
                    a3 = a2; b3 = b2; a2 = a1; b2 = b1; a1 = ov; b1 = oi;
                } else if (lexless(ov, oi, a2, b2)) {
                    a3 = a2; b3 = b2; a2 = ov; b2 = oi;
                } else if (lexless(ov, oi, a3, b3)) {
                    a3 = ov; b3 = oi;
                }
            }
        }
        if (col16 == 0) {
            int row = rowbase + koct * 4 + r;
            idx_out[row] = (float)b1;
            if (a2 - a1 < 0.5f * THETA) {           // scores are score/2
                if (a3 - a1 < 0.5f * THETA) {
                    unsigned slot = atomicAdd(fcnt, 1u);
                    fulllist[slot] = (unsigned)row;
                } else {
                    unsigned slot = atomicAdd(pcnt, 1u);
                    pairlist[slot] = make_uint2((unsigned)row,
                                                ((unsigned)b1 << 16) | (unsigned)b2);
                }
            }
        }
    }
}

// pair rescore: wave per ambiguous row; exact fp64 dots for the 2 candidates,
// np-emulated dref = fl(fl(szn+sen_k) - 2*fl32(dot64)), lex-min winner.
__global__ __launch_bounds__(256) void vq_fixpair(const float* __restrict__ z,
                                                  const float* __restrict__ cb,
                                                  const float* __restrict__ sen,
                                                  const float* __restrict__ szn,
                                                  const unsigned* __restrict__ pcnt,
                                                  const uint2* __restrict__ pairlist,
                                                  float* __restrict__ idx_out) {
    int wave = blockIdx.x * 4 + (threadIdx.x >> 6);
    int lane = threadIdx.x & 63;
    int half = lane >> 5, sub = lane & 31;
    int n = (int)*pcnt;
    for (int w = wave; w < n; w += gridDim.x * 4) {
        uint2 pr = pairlist[w];
        int row = (int)pr.x;
        int c1 = (int)(pr.y >> 16), c2 = (int)(pr.y & 0xffffu);
        int c = half ? c2 : c1;
        const float* zp = z + (size_t)row * DIM + sub * 8;
        const float* ep = cb + (size_t)c * DIM + sub * 8;
        float4 za = *(const float4*)zp, zb = *(const float4*)(zp + 4);
        float4 ea = *(const float4*)ep, eb = *(const float4*)(ep + 4);
        double acc = (double)ea.x * za.x + (double)ea.y * za.y
                   + (double)ea.z * za.z + (double)ea.w * za.w
                   + (double)eb.x * zb.x + (double)eb.y * zb.y
                   + (double)eb.z * zb.z + (double)eb.w * zb.w;
        #pragma unroll
        for (int m = 1; m < 32; m <<= 1) acc += __shfl_xor(acc, m, 64);
        double d2 = __shfl(acc, 32, 64);            // lane0 reads half-1 dot
        if (lane == 0) {
            float sz = szn[row];
            float A1 = __fadd_rn(sz, sen[c1]);
            float dref1 = __fmaf_rn(-2.0f, (float)acc, A1);
            float A2 = __fadd_rn(sz, sen[c2]);
            float dref2 = __fmaf_rn(-2.0f, (float)d2, A2);
            int win = lexless(dref1, c1, dref2, c2) ? c1 : c2;
            idx_out[row] = (float)win;
        }
    }
}

// full np-exact rescan for rows with >=3 candidates within theta (rare).
// Block per row; thread t owns codes 4t..4t+3.
__global__ __launch_bounds__(256) void vq_fixfull(const float* __restrict__ z,
                                                  const float* __restrict__ cb,
                                                  const float* __restrict__ sen,
                                                  const float* __restrict__ szn,
                                                  const unsigned* __restrict__ fcnt,
                                                  const unsigned* __restrict__ fulllist,
                                                  float* __restrict__ idx_out) {
    __shared__ float zrow[DIM];
    __shared__ float rv[256];
    __shared__ int ri[256];
    int t = threadIdx.x;
    int n = (int)*fcnt;
    for (int w = blockIdx.x; w < n; w += gridDim.x) {
        int row = (int)fulllist[w];
        float sz = szn[row];
        zrow[t] = z[(size_t)row * DIM + t];
        __syncthreads();
        float bv = 3.4e38f;
        int bi = 0x7fffffff;
        #pragma unroll
        for (int cc = 0; cc < 4; ++cc) {
            int c = t * 4 + cc;
            const float* e = cb + (size_t)c * DIM;
            double dot = 0.0;
            for (int d = 0; d < DIM; d += 4) {
                float4 ev = *(const float4*)(e + d);
                dot += (double)ev.x * zrow[d + 0] + (double)ev.y * zrow[d + 1]
                     + (double)ev.z * zrow[d + 2] + (double)ev.w * zrow[d + 3];
            }
            float dotx = (float)dot;
            float A = __fadd_rn(sz, sen[c]);
            float dref = __fmaf_rn(-2.0f, dotx, A);
            if (dref < bv) { bv = dref; bi = c; }   // ascending c: first-min
        }
        rv[t] = bv; ri[t] = bi;
        __syncthreads();
        for (int s = 128; s; s >>= 1) {
            if (t < s) {
                if (lexless(rv[t + s], ri[t + s], rv[t], ri[t])) {
                    rv[t] = rv[t + s]; ri[t] = ri[t + s];
                }
            }
            __syncthreads();
        }
        if (t == 0) idx_out[row] = (float)ri[0];
        __syncthreads();
    }
}

// quantized_ste = z + (q - z); commitment loss; histogram from final idx
__global__ __launch_bounds__(256) void vq_gather(const float* __restrict__ z,
                                                 const float* __restrict__ cb,
                                                 const float* __restrict__ idxf,
                                                 float* __restrict__ qout,
                                                 double* __restrict__ loss_acc,
                                                 unsigned* __restrict__ hist) {
    int gid = blockIdx.x * 256 + threadIdx.x;
    int row = gid >> 6, c4 = gid & 63;
    int idx = (int)idxf[row];
    if (c4 == 0) atomicAdd(&hist[idx], 1u);
    float4 zv = *(const float4*)(z + (size_t)row * DIM + c4 * 4);
    float4 qv = *(const float4*)(cb + (size_t)idx * DIM + c4 * 4);
    float dx = qv.x - zv.x, dy = qv.y - zv.y, dz = qv.z - zv.z, dw = qv.w - zv.w;
    float4 o;
    o.x = zv.x + dx; o.y = zv.y + dy; o.z = zv.z + dz; o.w = zv.w + dw;
    *(float4*)(qout + (size_t)row * DIM + c4 * 4) = o;
    float ls = dx * dx + dy * dy + dz * dz + dw * dw;
    #pragma unroll
    for (int off = 32; off; off >>= 1) ls += __shfl_down(ls, off, 64);
    __shared__ float wsum[4];
    int lane = threadIdx.x & 63, wv = threadIdx.x >> 6;
    if (lane == 0) wsum[wv] = ls;
    __syncthreads();
    if (threadIdx.x == 0)
        atomicAdd(loss_acc, (double)(wsum[0] + wsum[1] + wsum[2] + wsum[3]));
}

__global__ __launch_bounds__(1024) void vq_finalize(const unsigned* __restrict__ hist,
                                                    const double* __restrict__ loss_acc,
                                                    float* __restrict__ out) {
    __shared__ float red[1024];
    int t = threadIdx.x;
    float p = (float)hist[t] * (1.0f / (float)N_ROWS);
    red[t] = p * logf(p + 1e-10f);
    __syncthreads();
    for (int s = 512; s; s >>= 1) {
        if (t < s) red[t] += red[t + s];
        __syncthreads();
    }
    if (t == 0) {
        out[ZERO_OFF] = 0.0f;
        out[LOSS_OFF] = (float)(0.25 * (*loss_acc) / (double)Q_N);
        out[PERP_OFF] = expf(-red[0]);
    }
}

extern "C" void kernel_launch(void* const* d_in, const int* in_sizes, int n_in,
                              void* d_out, int out_size, void* d_ws, size_t ws_size,
                              hipStream_t stream) {
    const float* z = (const float*)d_in[0];
    const float* cb = (const float*)d_in[1];
    float* out = (float*)d_out;

    float* sen = (float*)d_ws;
    unsigned* hist = (unsigned*)((char*)d_ws + 4096);
    double* loss_acc = (double*)((char*)d_ws + 8192);
    unsigned* pcnt = (unsigned*)((char*)d_ws + 8200);
    unsigned* fcnt = (unsigned*)((char*)d_ws + 8204);
    float* szn = (float*)((char*)d_ws + 8448);
    uint2* pairlist = (uint2*)((char*)d_ws + 139520);
    unsigned* fulllist = (unsigned*)((char*)d_ws + 401664);
    u16* ehi = (u16*)((char*)d_ws + 532736);
    u16* elo = (u16*)((char*)d_ws + 1057024);

    u16* zhi = (u16*)d_out;
    u16* zlo = (u16*)d_out + Q_N;

    vq_prep_cb<<<KCODES / 4, 256, 0, stream>>>(cb, sen, ehi, elo, hist, loss_acc, pcnt, fcnt);
    vq_prep_z<<<N_ROWS / 4, 256, 0, stream>>>(z, zhi, zlo, szn);
    vq_mfma<<<N_ROWS / 64, 256, 0, stream>>>(zhi, zlo, ehi, elo, sen,
                                             out + IDX_OFF, pcnt, pairlist, fcnt, fulllist);
    vq_fixpair<<<256, 256, 0, stream>>>(z, cb, sen, szn, pcnt, pairlist, out + IDX_OFF);
    vq_fixfull<<<64, 256, 0, stream>>>(z, cb, sen, szn, fcnt, fulllist, out + IDX_OFF);
    vq_gather<<<(N_ROWS * (DIM / 4)) / 256, 256, 0, stream>>>(z, cb, out + IDX_OFF, out, loss_acc, hist);
    vq_finalize<<<1, 1024, 0, stream>>>(hist, loss_acc, out);
}

// Round 10
// 230.216 us; speedup vs baseline: 1.5680x; 1.1257x over previous
//
#include <hip/hip_runtime.h>

#define N_ROWS 32768
#define DIM 256
#define KCODES 1024

#define Q_N (N_ROWS * DIM)          // 8388608
#define IDX_OFF Q_N                 // 8388608
#define ZERO_OFF (Q_N + N_ROWS)     // 8421376
#define LOSS_OFF (ZERO_OFF + 1)
#define PERP_OFF (ZERO_OFF + 2)

// acc-unit (score/2) gap thresholds. np flip needs acc-gap <= 3.1e-5; our fast
// measurement error (bf16-split drop + mfma rounding + 2x key-trunc 3.8e-6)
// <= 1.4e-5. AMBIG=6e-5 covers 4.5e-5 with slack. Codes beyond FULLTH=1.2e-4
// of a1 can never beat the pair winner under np rounding (see round-10 notes).
#define AMBIG  6.0e-5f
#define FULLTH 1.2e-4f

#define TC 32                 // codes per LDS tile (mfma)
#define NT (KCODES / TC)      // 32 tiles
#define PAIR_BLOCKS 192

typedef __attribute__((ext_vector_type(8))) short bf16x8;
typedef __attribute__((ext_vector_type(4))) float f32x4;
typedef unsigned short u16;

// ws layout (bytes):
//   [0, 4096)            sen float[K]
//   [4096, 8192)         hist uint[K]
//   [8192, 8200)         double loss_acc
//   [8200, 8204)         uint pair_count
//   [8204, 8208)         uint full_count
//   [8448, 270592)       pairlist uint2[32768]  {row, c1<<16|c2}
//   [270592, 401664)     fulllist uint[32768]
//   [401664, 925952)     ehi u16[262144]    (bf16 of -e)
//   [925952, 1450240)    elo u16[262144]    (bf16 of (-e) - ehi)

__device__ inline u16 bf16rne(float f) {
    unsigned u = __float_as_uint(f);
    return (u16)((u + 0x7FFFu + ((u >> 16) & 1u)) >> 16);
}
__device__ inline float bf16f(u16 h) { return __uint_as_float((unsigned)h << 16); }

__device__ inline bool lexless(float av, int ai, float bv, int bi) {
    return av < bv || (av == bv && ai < bi);
}

typedef __attribute__((address_space(3))) unsigned int as3_uint;
typedef __attribute__((address_space(1))) const unsigned int as1_uint;
__device__ inline void gload_lds16(const void* g, void* l) {
    __builtin_amdgcn_global_load_lds((as1_uint*)g, (as3_uint*)l, 16, 0, 0);
}

// fused: init(hist/loss/counters) + accurate ||e||^2 + negated bf16 hi/lo splits.
__global__ __launch_bounds__(256) void vq_prep_cb(const float* __restrict__ cb,
                                                  float* __restrict__ sen,
                                                  u16* __restrict__ ehi,
                                                  u16* __restrict__ elo,
                                                  unsigned* __restrict__ hist,
                                                  double* __restrict__ loss_acc,
                                                  unsigned* __restrict__ pcnt,
                                                  unsigned* __restrict__ fcnt) {
    int b = blockIdx.x, t = threadIdx.x;
    if (b < 4) {
        hist[b * 256 + t] = 0u;
        if (b == 0 && t == 0) { *loss_acc = 0.0; *pcnt = 0u; *fcnt = 0u; }
    }
    int code = b * 4 + (t >> 6);
    int lane = t & 63;
    size_t eoff = (size_t)code * DIM + lane * 4;
    float4 v = *(const float4*)(cb + eoff);
    double s = (double)v.x * v.x + (double)v.y * v.y + (double)v.z * v.z + (double)v.w * v.w;
    #pragma unroll
    for (int off = 32; off; off >>= 1) s += __shfl_down(s, off, 64);
    if (lane == 0) sen[code] = (float)s;
    v.x = -v.x; v.y = -v.y; v.z = -v.z; v.w = -v.w;
    ushort4 h, l;
    h.x = bf16rne(v.x); l.x = bf16rne(v.x - bf16f(h.x));
    h.y = bf16rne(v.y); l.y = bf16rne(v.y - bf16f(h.y));
    h.z = bf16rne(v.z); l.z = bf16rne(v.z - bf16f(h.z));
    h.w = bf16rne(v.w); l.w = bf16rne(v.w - bf16f(h.w));
    *(ushort4*)(ehi + eoff) = h;
    *(ushort4*)(elo + eoff) = l;
}

// MFMA distance-argmin. 256 blocks x 8 waves x 16 rows/wave (2 blocks/CU via
// 64KB LDS, 4 waves/SIMD via <=128 VGPR). z split to bf16 hi/lo IN-REGISTER
// (prep_z kernel deleted). Packed-key top-3: s = 0.5 + 0.5*sen - dot (positive
// -> uint-monotone), key = (bits & ~63) | (tt*2+ct); running top-3 via
// min/clamp/med ops only. e-tiles staged via global_load_lds, double-buffered,
// T2 XOR-swizzle as inverse-swizzled SOURCE + swizzled READ (rule 21).
__global__ __launch_bounds__(512, 4) void vq_mfma(const float* __restrict__ z,
                                                  const u16* __restrict__ ehi,
                                                  const u16* __restrict__ elo,
                                                  const float* __restrict__ sen,
                                                  float* __restrict__ idx_out,
                                                  unsigned* __restrict__ pcnt,
                                                  uint2* __restrict__ pairlist,
                                                  unsigned* __restrict__ fcnt,
                                                  unsigned* __restrict__ fulllist) {
    __shared__ char lds[2][32768];   // per buffer: [0,16K) ehi tile, [16K,32K) elo tile
    const int tid = threadIdx.x;
    const int wid = tid >> 6;        // 0..7
    const int lane = tid & 63;
    const int col16 = lane & 15;
    const int koct = lane >> 4;
    const int s3 = col16 & 7;
    const int rowbase = blockIdx.x * 128 + wid * 16;

    // A fragments built in-register from fp32 z
    bf16x8 zh[8], zl[8];
    {
        const float* zp = z + (size_t)(rowbase + col16) * DIM + koct * 8;
        #pragma unroll
        for (int dc = 0; dc < 8; ++dc) {
            float4 f0 = *(const float4*)(zp + dc * 32);
            float4 f1 = *(const float4*)(zp + dc * 32 + 4);
            float f[8] = {f0.x, f0.y, f0.z, f0.w, f1.x, f1.y, f1.z, f1.w};
            bf16x8 hh, ll;
            #pragma unroll
            for (int j = 0; j < 8; ++j) {
                u16 hj = bf16rne(f[j]);
                hh[j] = (short)hj;
                ll[j] = (short)bf16rne(f[j] - bf16f(hj));
            }
            zh[dc] = hh; zl[dc] = ll;
        }
    }

    unsigned k1[4], k2[4], k3[4];
    #pragma unroll
    for (int r = 0; r < 4; ++r) { k1[r] = k2[r] = k3[r] = 0xFFFFFFFFu; }

    auto STAGE = [&](int tt, int b) {
        #pragma unroll
        for (int r = 0; r < 4; ++r) {
            int p = r * 512 + tid;
            int q = p & 1023;
            int src = q ^ ((q >> 5) & 7);          // inverse swizzle (involution)
            const char* sp = ((p >> 10) ? (const char*)elo : (const char*)ehi)
                             + (size_t)tt * 16384 + src * 16;
            gload_lds16(sp, &lds[b][p * 16]);
        }
    };

    STAGE(0, 0);
    __syncthreads();

    for (int tt = 0; tt < NT; ++tt) {
        if (tt + 1 < NT) STAGE(tt + 1, (tt + 1) & 1);
        const char* bb = lds[tt & 1];
        #pragma unroll
        for (int ct = 0; ct < 2; ++ct) {
            const int lc = ct * 16 + col16;
            const int c = tt * TC + lc;
            const float shb = fmaf(0.5f, sen[c], 0.5f);   // positive-bias C init
            const int rbase = lc * 512;
            f32x4 aHH = {shb, shb, shb, shb};
            f32x4 aLH = {0.f, 0.f, 0.f, 0.f};
            f32x4 aHL = {0.f, 0.f, 0.f, 0.f};
            #pragma unroll
            for (int dc = 0; dc < 8; ++dc) {
                int off = ((dc * 4 + koct) ^ s3) * 16;    // swizzled read
                bf16x8 bh = *(const bf16x8*)(bb + rbase + off);
                bf16x8 bl = *(const bf16x8*)(bb + 16384 + rbase + off);
                aHH = __builtin_amdgcn_mfma_f32_16x16x32_bf16(zh[dc], bh, aHH, 0, 0, 0);
                aLH = __builtin_amdgcn_mfma_f32_16x16x32_bf16(zl[dc], bh, aLH, 0, 0, 0);
                aHL = __builtin_amdgcn_mfma_f32_16x16x32_bf16(zh[dc], bl, aHL, 0, 0, 0);
            }
            const unsigned lidx = (unsigned)(tt * 2 + ct);
            #pragma unroll
            for (int r = 0; r < 4; ++r) {
                float s = aHH[r] + (aLH[r] + aHL[r]);
                unsigned key = (__float_as_uint(s) & 0xFFFFFFC0u) | lidx;
                unsigned o1 = k1[r];
                k1[r] = min(o1, key);                       // new min
                k3[r] = min(k3[r], max(k2[r], key));        // new 3rd (old k2)
                k2[r] = min(max(key, o1), k2[r]);           // med(o1,k2,key)
            }
        }
        __syncthreads();
    }

    #pragma unroll
    for (int r = 0; r < 4; ++r) {
        // decode (value, full code) triples
        float a1 = __uint_as_float(k1[r] & 0xFFFFFFC0u);
        float a2 = __uint_as_float(k2[r] & 0xFFFFFFC0u);
        float a3 = __uint_as_float(k3[r] & 0xFFFFFFC0u);
        int l1 = (int)(k1[r] & 63u), l2 = (int)(k2[r] & 63u), l3 = (int)(k3[r] & 63u);
        int b1 = (l1 >> 1) * 32 + (l1 & 1) * 16 + col16;
        int b2 = (l2 >> 1) * 32 + (l2 & 1) * 16 + col16;
        int b3 = (l3 >> 1) * 32 + (l3 & 1) * 16 + col16;
        #pragma unroll
        for (int m = 1; m < 16; m <<= 1) {
            float o1 = __shfl_xor(a1, m, 64), o2 = __shfl_xor(a2, m, 64), o3 = __shfl_xor(a3, m, 64);
            int p1 = __shfl_xor(b1, m, 64), p2 = __shfl_xor(b2, m, 64), p3 = __shfl_xor(b3, m, 64);
            #pragma unroll
            for (int k = 0; k < 3; ++k) {
                float ov = (k == 0) ? o1 : (k == 1) ? o2 : o3;
                int oi = (k == 0) ? p1 : (k == 1) ? p2 : p3;
                if (lexless(ov, oi, a1, b1)) {
                    a3 = a2; b3 = b2; a2 = a1; b2 = b1; a1 = ov; b1 = oi;
                } else if (lexless(ov, oi, a2, b2)) {
                    a3 = a2; b3 = b2; a2 = ov; b2 = oi;
                } else if (lexless(ov, oi, a3, b3)) {
                    a3 = ov; b3 = oi;
                }
            }
        }
        if (col16 == 0) {
            int row = rowbase + koct * 4 + r;
            idx_out[row] = (float)b1;
            if (a2 - a1 < AMBIG) {
                if (a3 - a1 < FULLTH) {
                    unsigned slot = atomicAdd(fcnt, 1u);
                    fulllist[slot] = (unsigned)row;
                } else {
                    unsigned slot = atomicAdd(pcnt, 1u);
                    pairlist[slot] = make_uint2((unsigned)row,
                                                ((unsigned)b1 << 16) | (unsigned)b2);
                }
            }
        }
    }
}

// np-pairwise ||z||^2 for one row, replicated in every 16-lane group of a wave
// (bit-exact np fp32 pairwise_sum order; see round-3 notes). All lanes return S.
__device__ inline float szn_wave(const float* __restrict__ zrow, int lane) {
    int sub = lane & 15;
    int hb = sub >> 3;
    int j = sub & 7;
    const float* a = zrow + hb * 128 + j;
    float v0 = a[0];
    float c = __fmul_rn(v0, v0);
    #pragma unroll
    for (int i = 1; i < 16; ++i) {
        float w = a[8 * i];
        c = __fadd_rn(c, __fmul_rn(w, w));
    }
    float p;
    p = __shfl_xor(c, 1, 64); c = __fadd_rn(c, p);
    p = __shfl_xor(c, 2, 64); c = __fadd_rn(c, p);
    p = __shfl_xor(c, 4, 64); c = __fadd_rn(c, p);
    p = __shfl_xor(c, 8, 64); c = __fadd_rn(c, p);
    return c;
}

// fused fix kernel. Blocks [0,192): wave-per-row pair rescore (2 exact fp64
// dots, np-emulated dref, lex-min). Blocks [192,256): block-per-row full
// np-exact rescan (rare; >=3 candidates near a1). szn computed on demand.
__global__ __launch_bounds__(256) void vq_fix(const float* __restrict__ z,
                                              const float* __restrict__ cb,
                                              const float* __restrict__ sen,
                                              const unsigned* __restrict__ pcnt,
                                              const uint2* __restrict__ pairlist,
                                              const unsigned* __restrict__ fcnt,
                                              const unsigned* __restrict__ fulllist,
                                              float* __restrict__ idx_out) {
    if (blockIdx.x < PAIR_BLOCKS) {
        int wave = blockIdx.x * 4 + (threadIdx.x >> 6);
        int lane = threadIdx.x & 63;
        int half = lane >> 5, s5 = lane & 31;
        int n = (int)*pcnt;
        for (int w = wave; w < n; w += PAIR_BLOCKS * 4) {
            uint2 pr = pairlist[w];
            int row = (int)pr.x;
            int c1 = (int)(pr.y >> 16), c2 = (int)(pr.y & 0xffffu);
            const float* zrow = z + (size_t)row * DIM;
            float sz = szn_wave(zrow, lane);
            int c = half ? c2 : c1;
            const float* zp = zrow + s5 * 8;
            const float* ep = cb + (size_t)c * DIM + s5 * 8;
            float4 za = *(const float4*)zp, zb = *(const float4*)(zp + 4);
            float4 ea = *(const float4*)ep, eb = *(const float4*)(ep + 4);
            double acc = (double)ea.x * za.x + (double)ea.y * za.y
                       + (double)ea.z * za.z + (double)ea.w * za.w
                       + (double)eb.x * zb.x + (double)eb.y * zb.y
                       + (double)eb.z * zb.z + (double)eb.w * zb.w;
            #pragma unroll
            for (int m = 1; m < 32; m <<= 1) acc += __shfl_xor(acc, m, 64);
            double d2 = __shfl(acc, 32, 64);            // lane0 reads half-1 dot
            if (lane == 0) {
                float A1 = __fadd_rn(sz, sen[c1]);
                float dref1 = __fmaf_rn(-2.0f, (float)acc, A1);
                float A2 = __fadd_rn(sz, sen[c2]);
                float dref2 = __fmaf_rn(-2.0f, (float)d2, A2);
                int win = lexless(dref1, c1, dref2, c2) ? c1 : c2;
                idx_out[row] = (float)win;
            }
        }
    } else {
        __shared__ float zrow[DIM];
        __shared__ float sz_s;
        __shared__ float rv[256];
        __shared__ int ri[256];
        int t = threadIdx.x;
        int n = (int)*fcnt;
        for (int w = blockIdx.x - PAIR_BLOCKS; w < n; w += 256 - PAIR_BLOCKS) {
            int row = (int)fulllist[w];
            zrow[t] = z[(size_t)row * DIM + t];
            __syncthreads();
            if (t < 64) {
                float sz = szn_wave(zrow, t);
                if (t == 0) sz_s = sz;
            }
            __syncthreads();
            float sz = sz_s;
            float bv = 3.4e38f;
            int bi = 0x7fffffff;
            #pragma unroll
            for (int cc = 0; cc < 4; ++cc) {
                int c = t * 4 + cc;
                const float* e = cb + (size_t)c * DIM;
                double dot = 0.0;
                for (int d = 0; d < DIM; d += 4) {
                    float4 ev = *(const float4*)(e + d);
                    dot += (double)ev.x * zrow[d + 0] + (double)ev.y * zrow[d + 1]
                         + (double)ev.z * zrow[d + 2] + (double)ev.w * zrow[d + 3];
                }
                float dotx = (float)dot;
                float A = __fadd_rn(sz, sen[c]);
                float dref = __fmaf_rn(-2.0f, dotx, A);
                if (dref < bv) { bv = dref; bi = c; }   // ascending c: first-min
            }
            rv[t] = bv; ri[t] = bi;
            __syncthreads();
            for (int s = 128; s; s >>= 1) {
                if (t < s) {
                    if (lexless(rv[t + s], ri[t + s], rv[t], ri[t])) {
                        rv[t] = rv[t + s]; ri[t] = ri[t + s];
                    }
                }
                __syncthreads();
            }
            if (t == 0) idx_out[row] = (float)ri[0];
            __syncthreads();
        }
    }
}

// quantized_ste = z + (q - z); commitment loss; histogram from final idx
__global__ __launch_bounds__(256) void vq_gather(const float* __restrict__ z,
                                                 const float* __restrict__ cb,
                                                 const float* __restrict__ idxf,
                                                 float* __restrict__ qout,
                                                 double* __restrict__ loss_acc,
                                                 unsigned* __restrict__ hist) {
    int gid = blockIdx.x * 256 + threadIdx.x;
    int row = gid >> 6, c4 = gid & 63;
    int idx = (int)idxf[row];
    if (c4 == 0) atomicAdd(&hist[idx], 1u);
    float4 zv = *(const float4*)(z + (size_t)row * DIM + c4 * 4);
    float4 qv = *(const float4*)(cb + (size_t)idx * DIM + c4 * 4);
    float dx = qv.x - zv.x, dy = qv.y - zv.y, dz = qv.z - zv.z, dw = qv.w - zv.w;
    float4 o;
    o.x = zv.x + dx; o.y = zv.y + dy; o.z = zv.z + dz; o.w = zv.w + dw;
    *(float4*)(qout + (size_t)row * DIM + c4 * 4) = o;
    float ls = dx * dx + dy * dy + dz * dz + dw * dw;
    #pragma unroll
    for (int off = 32; off; off >>= 1) ls += __shfl_down(ls, off, 64);
    __shared__ float wsum[4];
    int lane = threadIdx.x & 63, wv = threadIdx.x >> 6;
    if (lane == 0) wsum[wv] = ls;
    __syncthreads();
    if (threadIdx.x == 0)
        atomicAdd(loss_acc, (double)(wsum[0] + wsum[1] + wsum[2] + wsum[3]));
}

__global__ __launch_bounds__(1024) void vq_finalize(const unsigned* __restrict__ hist,
                                                    const double* __restrict__ loss_acc,
                                                    float* __restrict__ out) {
    __shared__ float red[1024];
    int t = threadIdx.x;
    float p = (float)hist[t] * (1.0f / (float)N_ROWS);
    red[t] = p * logf(p + 1e-10f);
    __syncthreads();
    for (int s = 512; s; s >>= 1) {
        if (t < s) red[t] += red[t + s];
        __syncthreads();
    }
    if (t == 0) {
        out[ZERO_OFF] = 0.0f;
        out[LOSS_OFF] = (float)(0.25 * (*loss_acc) / (double)Q_N);
        out[PERP_OFF] = expf(-red[0]);
    }
}

extern "C" void kernel_launch(void* const* d_in, const int* in_sizes, int n_in,
                              void* d_out, int out_size, void* d_ws, size_t ws_size,
                              hipStream_t stream) {
    const float* z = (const float*)d_in[0];
    const float* cb = (const float*)d_in[1];
    float* out = (float*)d_out;

    float* sen = (float*)d_ws;
    unsigned* hist = (unsigned*)((char*)d_ws + 4096);
    double* loss_acc = (double*)((char*)d_ws + 8192);
    unsigned* pcnt = (unsigned*)((char*)d_ws + 8200);
    unsigned* fcnt = (unsigned*)((char*)d_ws + 8204);
    uint2* pairlist = (uint2*)((char*)d_ws + 8448);
    unsigned* fulllist = (unsigned*)((char*)d_ws + 270592);
    u16* ehi = (u16*)((char*)d_ws + 401664);
    u16* elo = (u16*)((char*)d_ws + 925952);

    vq_prep_cb<<<KCODES / 4, 256, 0, stream>>>(cb, sen, ehi, elo, hist, loss_acc, pcnt, fcnt);
    vq_mfma<<<N_ROWS / 128, 512, 0, stream>>>(z, ehi, elo, sen,
                                              out + IDX_OFF, pcnt, pairlist, fcnt, fulllist);
    vq_fix<<<256, 256, 0, stream>>>(z, cb, sen, pcnt, pairlist, fcnt, fulllist, out + IDX_OFF);
    vq_gather<<<(N_ROWS * (DIM / 4)) / 256, 256, 0, stream>>>(z, cb, out + IDX_OFF, out, loss_acc, hist);
    vq_finalize<<<1, 1024, 0, stream>>>(hist, loss_acc, out);
}

// Round 11
// 142.065 us; speedup vs baseline: 2.5410x; 1.6205x over previous
//
#include <hip/hip_runtime.h>

#define N_ROWS 32768
#define DIM 256
#define KCODES 1024

#define Q_N (N_ROWS * DIM)          // 8388608
#define IDX_OFF Q_N                 // 8388608
#define ZERO_OFF (Q_N + N_ROWS)     // 8421376
#define LOSS_OFF (ZERO_OFF + 1)
#define PERP_OFF (ZERO_OFF + 2)

// acc-unit (score/2) gap thresholds. np flip needs acc-gap <= 3.1e-5; our fast
// measurement error (bf16-split drop + mfma rounding + 2x key-trunc 3.8e-6)
// <= 1.4e-5. AMBIG=6e-5 covers 4.5e-5 with slack. Codes beyond FULLTH=1.2e-4
// of a1 can never beat the pair winner under np rounding.
#define AMBIG  6.0e-5f
#define FULLTH 1.2e-4f

#define TC 32                 // codes per LDS tile (mfma)
#define NT (KCODES / TC)      // 32 tiles
#define PAIR_BLOCKS 192
#define GATHER_BLOCKS 1024
#define GATHER_ITERS 8        // 1024*256*8 = 2M float4 = N_ROWS*DIM/4

typedef __attribute__((ext_vector_type(8))) short bf16x8;
typedef __attribute__((ext_vector_type(4))) float f32x4;
typedef unsigned short u16;

// ws layout (bytes):
//   [0, 4096)            sen float[K]
//   [4096, 8192)         hist uint[K]
//   [8192, 8196)         uint pair_count
//   [8196, 8200)         uint full_count
//   [8448, 270592)       pairlist uint2[32768]  {row, c1<<16|c2}
//   [270592, 401664)     fulllist uint[32768]
//   [401664, 925952)     ehi u16[262144]    (bf16 of -e)
//   [925952, 1450240)    elo u16[262144]    (bf16 of (-e) - ehi)
//   [1450240, 1458432)   partials double[1024]  (per-block loss sums)

__device__ inline u16 bf16rne(float f) {
    unsigned u = __float_as_uint(f);
    return (u16)((u + 0x7FFFu + ((u >> 16) & 1u)) >> 16);
}
__device__ inline float bf16f(u16 h) { return __uint_as_float((unsigned)h << 16); }

__device__ inline bool lexless(float av, int ai, float bv, int bi) {
    return av < bv || (av == bv && ai < bi);
}

typedef __attribute__((address_space(3))) unsigned int as3_uint;
typedef __attribute__((address_space(1))) const unsigned int as1_uint;
__device__ inline void gload_lds16(const void* g, void* l) {
    __builtin_amdgcn_global_load_lds((as1_uint*)g, (as3_uint*)l, 16, 0, 0);
}

// fused: init(hist/counters) + accurate ||e||^2 + negated bf16 hi/lo splits.
__global__ __launch_bounds__(256) void vq_prep_cb(const float* __restrict__ cb,
                                                  float* __restrict__ sen,
                                                  u16* __restrict__ ehi,
                                                  u16* __restrict__ elo,
                                                  unsigned* __restrict__ hist,
                                                  unsigned* __restrict__ pcnt,
                                                  unsigned* __restrict__ fcnt) {
    int b = blockIdx.x, t = threadIdx.x;
    if (b < 4) {
        hist[b * 256 + t] = 0u;
        if (b == 0 && t == 0) { *pcnt = 0u; *fcnt = 0u; }
    }
    int code = b * 4 + (t >> 6);
    int lane = t & 63;
    size_t eoff = (size_t)code * DIM + lane * 4;
    float4 v = *(const float4*)(cb + eoff);
    double s = (double)v.x * v.x + (double)v.y * v.y + (double)v.z * v.z + (double)v.w * v.w;
    #pragma unroll
    for (int off = 32; off; off >>= 1) s += __shfl_down(s, off, 64);
    if (lane == 0) sen[code] = (float)s;
    v.x = -v.x; v.y = -v.y; v.z = -v.z; v.w = -v.w;
    ushort4 h, l;
    h.x = bf16rne(v.x); l.x = bf16rne(v.x - bf16f(h.x));
    h.y = bf16rne(v.y); l.y = bf16rne(v.y - bf16f(h.y));
    h.z = bf16rne(v.z); l.z = bf16rne(v.z - bf16f(h.z));
    h.w = bf16rne(v.w); l.w = bf16rne(v.w - bf16f(h.w));
    *(ushort4*)(ehi + eoff) = h;
    *(ushort4*)(elo + eoff) = l;
}

// MFMA distance-argmin (unchanged from round 10).
__global__ __launch_bounds__(512, 4) void vq_mfma(const float* __restrict__ z,
                                                  const u16* __restrict__ ehi,
                                                  const u16* __restrict__ elo,
                                                  const float* __restrict__ sen,
                                                  float* __restrict__ idx_out,
                                                  unsigned* __restrict__ pcnt,
                                                  uint2* __restrict__ pairlist,
                                                  unsigned* __restrict__ fcnt,
                                                  unsigned* __restrict__ fulllist) {
    __shared__ char lds[2][32768];   // per buffer: [0,16K) ehi tile, [16K,32K) elo tile
    const int tid = threadIdx.x;
    const int wid = tid >> 6;        // 0..7
    const int lane = tid & 63;
    const int col16 = lane & 15;
    const int koct = lane >> 4;
    const int s3 = col16 & 7;
    const int rowbase = blockIdx.x * 128 + wid * 16;

    // A fragments built in-register from fp32 z
    bf16x8 zh[8], zl[8];
    {
        const float* zp = z + (size_t)(rowbase + col16) * DIM + koct * 8;
        #pragma unroll
        for (int dc = 0; dc < 8; ++dc) {
            float4 f0 = *(const float4*)(zp + dc * 32);
            float4 f1 = *(const float4*)(zp + dc * 32 + 4);
            float f[8] = {f0.x, f0.y, f0.z, f0.w, f1.x, f1.y, f1.z, f1.w};
            bf16x8 hh, ll;
            #pragma unroll
            for (int j = 0; j < 8; ++j) {
                u16 hj = bf16rne(f[j]);
                hh[j] = (short)hj;
                ll[j] = (short)bf16rne(f[j] - bf16f(hj));
            }
            zh[dc] = hh; zl[dc] = ll;
        }
    }

    unsigned k1[4], k2[4], k3[4];
    #pragma unroll
    for (int r = 0; r < 4; ++r) { k1[r] = k2[r] = k3[r] = 0xFFFFFFFFu; }

    auto STAGE = [&](int tt, int b) {
        #pragma unroll
        for (int r = 0; r < 4; ++r) {
            int p = r * 512 + tid;
            int q = p & 1023;
            int src = q ^ ((q >> 5) & 7);          // inverse swizzle (involution)
            const char* sp = ((p >> 10) ? (const char*)elo : (const char*)ehi)
                             + (size_t)tt * 16384 + src * 16;
            gload_lds16(sp, &lds[b][p * 16]);
        }
    };

    STAGE(0, 0);
    __syncthreads();

    for (int tt = 0; tt < NT; ++tt) {
        if (tt + 1 < NT) STAGE(tt + 1, (tt + 1) & 1);
        const char* bb = lds[tt & 1];
        #pragma unroll
        for (int ct = 0; ct < 2; ++ct) {
            const int lc = ct * 16 + col16;
            const int c = tt * TC + lc;
            const float shb = fmaf(0.5f, sen[c], 0.5f);   // positive-bias C init
            const int rbase = lc * 512;
            f32x4 aHH = {shb, shb, shb, shb};
            f32x4 aLH = {0.f, 0.f, 0.f, 0.f};
            f32x4 aHL = {0.f, 0.f, 0.f, 0.f};
            #pragma unroll
            for (int dc = 0; dc < 8; ++dc) {
                int off = ((dc * 4 + koct) ^ s3) * 16;    // swizzled read
                bf16x8 bh = *(const bf16x8*)(bb + rbase + off);
                bf16x8 bl = *(const bf16x8*)(bb + 16384 + rbase + off);
                aHH = __builtin_amdgcn_mfma_f32_16x16x32_bf16(zh[dc], bh, aHH, 0, 0, 0);
                aLH = __builtin_amdgcn_mfma_f32_16x16x32_bf16(zl[dc], bh, aLH, 0, 0, 0);
                aHL = __builtin_amdgcn_mfma_f32_16x16x32_bf16(zh[dc], bl, aHL, 0, 0, 0);
            }
            const unsigned lidx = (unsigned)(tt * 2 + ct);
            #pragma unroll
            for (int r = 0; r < 4; ++r) {
                float s = aHH[r] + (aLH[r] + aHL[r]);
                unsigned key = (__float_as_uint(s) & 0xFFFFFFC0u) | lidx;
                unsigned o1 = k1[r];
                k1[r] = min(o1, key);                       // new min
                k3[r] = min(k3[r], max(k2[r], key));        // new 3rd (old k2)
                k2[r] = min(max(key, o1), k2[r]);           // med(o1,k2,key)
            }
        }
        __syncthreads();
    }

    #pragma unroll
    for (int r = 0; r < 4; ++r) {
        float a1 = __uint_as_float(k1[r] & 0xFFFFFFC0u);
        float a2 = __uint_as_float(k2[r] & 0xFFFFFFC0u);
        float a3 = __uint_as_float(k3[r] & 0xFFFFFFC0u);
        int l1 = (int)(k1[r] & 63u), l2 = (int)(k2[r] & 63u), l3 = (int)(k3[r] & 63u);
        int b1 = (l1 >> 1) * 32 + (l1 & 1) * 16 + col16;
        int b2 = (l2 >> 1) * 32 + (l2 & 1) * 16 + col16;
        int b3 = (l3 >> 1) * 32 + (l3 & 1) * 16 + col16;
        #pragma unroll
        for (int m = 1; m < 16; m <<= 1) {
            float o1 = __shfl_xor(a1, m, 64), o2 = __shfl_xor(a2, m, 64), o3 = __shfl_xor(a3, m, 64);
            int p1 = __shfl_xor(b1, m, 64), p2 = __shfl_xor(b2, m, 64), p3 = __shfl_xor(b3, m, 64);
            #pragma unroll
            for (int k = 0; k < 3; ++k) {
                float ov = (k == 0) ? o1 : (k == 1) ? o2 : o3;
                int oi = (k == 0) ? p1 : (k == 1) ? p2 : p3;
                if (lexless(ov, oi, a1, b1)) {
                    a3 = a2; b3 = b2; a2 = a1; b2 = b1; a1 = ov; b1 = oi;
                } else if (lexless(ov, oi, a2, b2)) {
                    a3 = a2; b3 = b2; a2 = ov; b2 = oi;
                } else if (lexless(ov, oi, a3, b3)) {
                    a3 = ov; b3 = oi;
                }
            }
        }
        if (col16 == 0) {
            int row = rowbase + koct * 4 + r;
            idx_out[row] = (float)b1;
            if (a2 - a1 < AMBIG) {
                if (a3 - a1 < FULLTH) {
                    unsigned slot = atomicAdd(fcnt, 1u);
                    fulllist[slot] = (unsigned)row;
                } else {
                    unsigned slot = atomicAdd(pcnt, 1u);
                    pairlist[slot] = make_uint2((unsigned)row,
                                                ((unsigned)b1 << 16) | (unsigned)b2);
                }
            }
        }
    }
}

// np-pairwise ||z||^2 for one row, replicated in every 16-lane group of a wave.
__device__ inline float szn_wave(const float* __restrict__ zrow, int lane) {
    int sub = lane & 15;
    int hb = sub >> 3;
    int j = sub & 7;
    const float* a = zrow + hb * 128 + j;
    float v0 = a[0];
    float c = __fmul_rn(v0, v0);
    #pragma unroll
    for (int i = 1; i < 16; ++i) {
        float w = a[8 * i];
        c = __fadd_rn(c, __fmul_rn(w, w));
    }
    float p;
    p = __shfl_xor(c, 1, 64); c = __fadd_rn(c, p);
    p = __shfl_xor(c, 2, 64); c = __fadd_rn(c, p);
    p = __shfl_xor(c, 4, 64); c = __fadd_rn(c, p);
    p = __shfl_xor(c, 8, 64); c = __fadd_rn(c, p);
    return c;
}

// fused fix kernel (unchanged from round 10).
__global__ __launch_bounds__(256) void vq_fix(const float* __restrict__ z,
                                              const float* __restrict__ cb,
                                              const float* __restrict__ sen,
                                              const unsigned* __restrict__ pcnt,
                                              const uint2* __restrict__ pairlist,
                                              const unsigned* __restrict__ fcnt,
                                              const unsigned* __restrict__ fulllist,
                                              float* __restrict__ idx_out) {
    if (blockIdx.x < PAIR_BLOCKS) {
        int wave = blockIdx.x * 4 + (threadIdx.x >> 6);
        int lane = threadIdx.x & 63;
        int half = lane >> 5, s5 = lane & 31;
        int n = (int)*pcnt;
        for (int w = wave; w < n; w += PAIR_BLOCKS * 4) {
            uint2 pr = pairlist[w];
            int row = (int)pr.x;
            int c1 = (int)(pr.y >> 16), c2 = (int)(pr.y & 0xffffu);
            const float* zrow = z + (size_t)row * DIM;
            float sz = szn_wave(zrow, lane);
            int c = half ? c2 : c1;
            const float* zp = zrow + s5 * 8;
            const float* ep = cb + (size_t)c * DIM + s5 * 8;
            float4 za = *(const float4*)zp, zb = *(const float4*)(zp + 4);
            float4 ea = *(const float4*)ep, eb = *(const float4*)(ep + 4);
            double acc = (double)ea.x * za.x + (double)ea.y * za.y
                       + (double)ea.z * za.z + (double)ea.w * za.w
                       + (double)eb.x * zb.x + (double)eb.y * zb.y
                       + (double)eb.z * zb.z + (double)eb.w * zb.w;
            #pragma unroll
            for (int m = 1; m < 32; m <<= 1) acc += __shfl_xor(acc, m, 64);
            double d2 = __shfl(acc, 32, 64);            // lane0 reads half-1 dot
            if (lane == 0) {
                float A1 = __fadd_rn(sz, sen[c1]);
                float dref1 = __fmaf_rn(-2.0f, (float)acc, A1);
                float A2 = __fadd_rn(sz, sen[c2]);
                float dref2 = __fmaf_rn(-2.0f, (float)d2, A2);
                int win = lexless(dref1, c1, dref2, c2) ? c1 : c2;
                idx_out[row] = (float)win;
            }
        }
    } else {
        __shared__ float zrow[DIM];
        __shared__ float sz_s;
        __shared__ float rv[256];
        __shared__ int ri[256];
        int t = threadIdx.x;
        int n = (int)*fcnt;
        for (int w = blockIdx.x - PAIR_BLOCKS; w < n; w += 256 - PAIR_BLOCKS) {
            int row = (int)fulllist[w];
            zrow[t] = z[(size_t)row * DIM + t];
            __syncthreads();
            if (t < 64) {
                float sz = szn_wave(zrow, t);
                if (t == 0) sz_s = sz;
            }
            __syncthreads();
            float sz = sz_s;
            float bv = 3.4e38f;
            int bi = 0x7fffffff;
            #pragma unroll
            for (int cc = 0; cc < 4; ++cc) {
                int c = t * 4 + cc;
                const float* e = cb + (size_t)c * DIM;
                double dot = 0.0;
                for (int d = 0; d < DIM; d += 4) {
                    float4 ev = *(const float4*)(e + d);
                    dot += (double)ev.x * zrow[d + 0] + (double)ev.y * zrow[d + 1]
                         + (double)ev.z * zrow[d + 2] + (double)ev.w * zrow[d + 3];
                }
                float dotx = (float)dot;
                float A = __fadd_rn(sz, sen[c]);
                float dref = __fmaf_rn(-2.0f, dotx, A);
                if (dref < bv) { bv = dref; bi = c; }   // ascending c: first-min
            }
            rv[t] = bv; ri[t] = bi;
            __syncthreads();
            for (int s = 128; s; s >>= 1) {
                if (t < s) {
                    if (lexless(rv[t + s], ri[t + s], rv[t], ri[t])) {
                        rv[t] = rv[t + s]; ri[t] = ri[t + s];
                    }
                }
                __syncthreads();
            }
            if (t == 0) idx_out[row] = (float)ri[0];
            __syncthreads();
        }
    }
}

// quantized_ste + commitment loss + histogram. NO same-address atomics:
// per-block loss partial -> partials[blockIdx], reduced in vq_finalize.
// 1024 blocks x 256 thr x 8 grid-strided float4 iters (coalesced).
__global__ __launch_bounds__(256) void vq_gather(const float* __restrict__ z,
                                                 const float* __restrict__ cb,
                                                 const float* __restrict__ idxf,
                                                 float* __restrict__ qout,
                                                 unsigned* __restrict__ hist,
                                                 double* __restrict__ partials) {
    const int tid = threadIdx.x;
    double lacc = 0.0;
    #pragma unroll
    for (int it = 0; it < GATHER_ITERS; ++it) {
        int g = it * (GATHER_BLOCKS * 256) + blockIdx.x * 256 + tid;
        int row = g >> 6, c4 = g & 63;
        int idx = (int)idxf[row];
        if (c4 == 0) atomicAdd(&hist[idx], 1u);
        float4 zv = *(const float4*)(z + (size_t)g * 4);
        float4 qv = *(const float4*)(cb + (size_t)idx * DIM + c4 * 4);
        float dx = qv.x - zv.x, dy = qv.y - zv.y, dz = qv.z - zv.z, dw = qv.w - zv.w;
        float4 o;
        o.x = zv.x + dx; o.y = zv.y + dy; o.z = zv.z + dz; o.w = zv.w + dw;
        *(float4*)(qout + (size_t)g * 4) = o;
        lacc += (double)(dx * dx + dy * dy + dz * dz + dw * dw);
    }
    #pragma unroll
    for (int off = 32; off; off >>= 1) lacc += __shfl_down(lacc, off, 64);
    __shared__ double wsum[4];
    int lane = tid & 63, wv = tid >> 6;
    if (lane == 0) wsum[wv] = lacc;
    __syncthreads();
    if (tid == 0)
        partials[blockIdx.x] = (wsum[0] + wsum[1]) + (wsum[2] + wsum[3]);
}

// reduce 1024 loss partials (double) + hist entropy -> 3 scalars
__global__ __launch_bounds__(1024) void vq_finalize(const unsigned* __restrict__ hist,
                                                    const double* __restrict__ partials,
                                                    float* __restrict__ out) {
    __shared__ float red[1024];
    __shared__ double redd[1024];
    int t = threadIdx.x;
    float p = (float)hist[t] * (1.0f / (float)N_ROWS);
    red[t] = p * logf(p + 1e-10f);
    redd[t] = partials[t];
    __syncthreads();
    for (int s = 512; s; s >>= 1) {
        if (t < s) { red[t] += red[t + s]; redd[t] += redd[t + s]; }
        __syncthreads();
    }
    if (t == 0) {
        out[ZERO_OFF] = 0.0f;
        out[LOSS_OFF] = (float)(0.25 * redd[0] / (double)Q_N);
        out[PERP_OFF] = expf(-red[0]);
    }
}

extern "C" void kernel_launch(void* const* d_in, const int* in_sizes, int n_in,
                              void* d_out, int out_size, void* d_ws, size_t ws_size,
                              hipStream_t stream) {
    const float* z = (const float*)d_in[0];
    const float* cb = (const float*)d_in[1];
    float* out = (float*)d_out;

    float* sen = (float*)d_ws;
    unsigned* hist = (unsigned*)((char*)d_ws + 4096);
    unsigned* pcnt = (unsigned*)((char*)d_ws + 8192);
    unsigned* fcnt = (unsigned*)((char*)d_ws + 8196);
    uint2* pairlist = (uint2*)((char*)d_ws + 8448);
    unsigned* fulllist = (unsigned*)((char*)d_ws + 270592);
    u16* ehi = (u16*)((char*)d_ws + 401664);
    u16* elo = (u16*)((char*)d_ws + 925952);
    double* partials = (double*)((char*)d_ws + 1450240);

    vq_prep_cb<<<KCODES / 4, 256, 0, stream>>>(cb, sen, ehi, elo, hist, pcnt, fcnt);
    vq_mfma<<<N_ROWS / 128, 512, 0, stream>>>(z, ehi, elo, sen,
                                              out + IDX_OFF, pcnt, pairlist, fcnt, fulllist);
    vq_fix<<<256, 256, 0, stream>>>(z, cb, sen, pcnt, pairlist, fcnt, fulllist, out + IDX_OFF);
    vq_gather<<<GATHER_BLOCKS, 256, 0, stream>>>(z, cb, out + IDX_OFF, out, hist, partials);
    vq_finalize<<<1, 1024, 0, stream>>>(hist, partials, out);
}